// Round 2
// baseline (213222.778 us; speedup 1.0000x reference)
//
#include <hip/hip_runtime.h>
#include <math.h>

#define IQ     64
#define C_CH   256
#define T_SEQ  1024
#define NSTEP  (IQ * T_SEQ)
#define BATCH  4   // steps per register batch (u prefetch / x writeback granularity)

// ---------------------------------------------------------------------------
// GEMM in [iq][c][t] layout:
//   Out[iq][c][t] = act( sum_j A[c][j] * In[iq][j][t] (+ bias[c]) )
// Tiles: 64 c x 64 t per block, K staged in chunks of 64. 256 threads.
// Used for (A=M, In=u)  -> Uproj   (no activation)
// and      (A=H, In=X)  -> Y       (sigmoid + bias)
// ---------------------------------------------------------------------------
template <bool SIG>
__global__ void __launch_bounds__(256) gemm_ct(const float* __restrict__ A,
                                               const float* __restrict__ In,
                                               const float* __restrict__ bias,
                                               float* __restrict__ Out) {
    __shared__ float aT[64][65];  // [jj][c]  (A transposed tile, padded)
    __shared__ float bI[64][68];  // [jj][t]  (In tile, padded, 16B-aligned rows)

    const int tid = threadIdx.x;
    const int t0  = blockIdx.x * 64;
    const int c0  = blockIdx.y * 64;
    const int iq  = blockIdx.z;

    const int tt = tid & 15;   // t-quad index (compute mapping)
    const int cc = tid >> 4;   // c-quad index
    const int lr = tid >> 2;   // row for loads
    const int lq = tid & 3;    // quad-column for loads

    float acc[4][4];
#pragma unroll
    for (int m = 0; m < 4; ++m)
#pragma unroll
        for (int n = 0; n < 4; ++n) acc[m][n] = 0.f;

    for (int kc = 0; kc < 4; ++kc) {
        const float* Ar = A + (size_t)(c0 + lr) * 256 + kc * 64;
#pragma unroll
        for (int k2 = 0; k2 < 4; ++k2) {
            float4 v = *(const float4*)(Ar + lq * 4 + k2 * 16);
            int jj = lq * 4 + k2 * 16;
            aT[jj + 0][lr] = v.x;
            aT[jj + 1][lr] = v.y;
            aT[jj + 2][lr] = v.z;
            aT[jj + 3][lr] = v.w;
        }
        const float* Ir = In + ((size_t)iq * 256 + kc * 64 + lr) * 1024 + t0;
#pragma unroll
        for (int k2 = 0; k2 < 4; ++k2) {
            float4 v = *(const float4*)(Ir + lq * 4 + k2 * 16);
            *(float4*)&bI[lr][lq * 4 + k2 * 16] = v;
        }
        __syncthreads();

#pragma unroll 8
        for (int jj = 0; jj < 64; ++jj) {
            const float a0 = aT[jj][cc * 4 + 0];
            const float a1 = aT[jj][cc * 4 + 1];
            const float a2 = aT[jj][cc * 4 + 2];
            const float a3 = aT[jj][cc * 4 + 3];
            const float4 b4 = *(const float4*)&bI[jj][tt * 4];
            acc[0][0] = fmaf(a0, b4.x, acc[0][0]);
            acc[0][1] = fmaf(a0, b4.y, acc[0][1]);
            acc[0][2] = fmaf(a0, b4.z, acc[0][2]);
            acc[0][3] = fmaf(a0, b4.w, acc[0][3]);
            acc[1][0] = fmaf(a1, b4.x, acc[1][0]);
            acc[1][1] = fmaf(a1, b4.y, acc[1][1]);
            acc[1][2] = fmaf(a1, b4.z, acc[1][2]);
            acc[1][3] = fmaf(a1, b4.w, acc[1][3]);
            acc[2][0] = fmaf(a2, b4.x, acc[2][0]);
            acc[2][1] = fmaf(a2, b4.y, acc[2][1]);
            acc[2][2] = fmaf(a2, b4.z, acc[2][2]);
            acc[2][3] = fmaf(a2, b4.w, acc[2][3]);
            acc[3][0] = fmaf(a3, b4.x, acc[3][0]);
            acc[3][1] = fmaf(a3, b4.y, acc[3][1]);
            acc[3][2] = fmaf(a3, b4.z, acc[3][2]);
            acc[3][3] = fmaf(a3, b4.w, acc[3][3]);
        }
        __syncthreads();
    }

#pragma unroll
    for (int m = 0; m < 4; ++m) {
        const int c = c0 + cc * 4 + m;
        float4 v;
        if constexpr (SIG) {
            const float bb = bias[c];
            v.x = __fdividef(1.f, 1.f + __expf(-(acc[m][0] + bb)));
            v.y = __fdividef(1.f, 1.f + __expf(-(acc[m][1] + bb)));
            v.z = __fdividef(1.f, 1.f + __expf(-(acc[m][2] + bb)));
            v.w = __fdividef(1.f, 1.f + __expf(-(acc[m][3] + bb)));
        } else {
            v.x = acc[m][0];
            v.y = acc[m][1];
            v.z = acc[m][2];
            v.w = acc[m][3];
        }
        *(float4*)(Out + ((size_t)iq * 256 + c) * 1024 + t0 + tt * 4) = v;
    }
}

// ---------------------------------------------------------------------------
// Sequential scan, restructured: 256 threads (4 waves), 1 channel per lane.
//   - W row (256 floats) per lane in VGPRs -> matvec needs NO reduction.
//   - x, tanh update fully per-lane (no leader phase).
//   - tanh(x) exchanged via double-buffered LDS; ONE raw barrier per step
//     (s_waitcnt lgkmcnt(0) + s_barrier), so u-prefetch / x-writeback vmem
//     ops stay in flight across steps.
//   - Uproj in [iq][c][t] (out0 region); X written [iq][c][t] (out1 region).
// ---------------------------------------------------------------------------
__global__ void __launch_bounds__(256, 1) scan_kernel(const float* __restrict__ W,
                                                      const float* __restrict__ Up,
                                                      const float* __restrict__ dtp,
                                                      float* __restrict__ Xout) {
    __shared__ float tx0[C_CH];  // tanh(x), parity-0 buffer
    __shared__ float tx1[C_CH];  // tanh(x), parity-1 buffer

    const int l = threadIdx.x;   // lane == channel
    const float dt = *dtp;

    // Preload W row for this channel into registers (256 VGPRs).
    float w[256];
    {
        const float* Wr = W + (size_t)l * 256;
#pragma unroll
        for (int k = 0; k < 64; ++k) {
            float4 v = *(const float4*)(Wr + 4 * k);
            w[4 * k + 0] = v.x;
            w[4 * k + 1] = v.y;
            w[4 * k + 2] = v.z;
            w[4 * k + 3] = v.w;
        }
    }

    float x = 0.f;
    tx0[l] = 0.f;  // tanh(x0) = 0
    __syncthreads();

    float ua[BATCH], ub[BATCH], xh[BATCH];

    // Preload u batch 0 (steps 0..3) into ua.
    {
        float4 v = *(const float4*)(Up + (size_t)l * 1024);
        ua[0] = v.x; ua[1] = v.y; ua[2] = v.z; ua[3] = v.w;
    }

    // One macro-iteration = 2 batches (ping-pong ua/ub) = 8 steps.
#pragma unroll 1
    for (int it = 0; it < NSTEP / (2 * BATCH); ++it) {
        const int sA = it * 2 * BATCH;          // phase A start step
        const int sB = sA + BATCH;              // phase B start step

        // ----- phase A: steps sA..sA+3 using ua; prefetch ub for sB -----
        {
            // Prefetch next batch (phase B). Last-iter overrun reads into the
            // out1 region of d_out (in-bounds, values unused).
            const float* p = Up + (((size_t)(sB >> 10) << 8) + l) * 1024 + (sB & 1023);
            float4 v = *(const float4*)p;
            ub[0] = v.x; ub[1] = v.y; ub[2] = v.z; ub[3] = v.w;
        }
#pragma unroll
        for (int sub = 0; sub < BATCH; ++sub) {
            const float4* txp = (const float4*)((sub & 1) ? tx1 : tx0);
            float*        txw = (sub & 1) ? tx0 : tx1;
            float a0 = 0.f, a1 = 0.f, a2 = 0.f, a3 = 0.f;
#pragma unroll
            for (int k = 0; k < 64; ++k) {
                const float4 t = txp[k];  // wave-uniform ds_read_b128 (broadcast)
                a0 = fmaf(w[4 * k + 0], t.x, a0);
                a1 = fmaf(w[4 * k + 1], t.y, a1);
                a2 = fmaf(w[4 * k + 2], t.z, a2);
                a3 = fmaf(w[4 * k + 3], t.w, a3);
            }
            const float sum = (a0 + a1) + (a2 + a3);
            const float inp = sum + ua[sub];
            x = fmaf(dt, inp - x, x);           // x + dt*(-x + inp)
            xh[sub] = x;
            const float av = fabsf(x);
            const float e  = __expf(-2.f * av);
            const float th = (1.f - e) * __fdividef(1.f, 1.f + e);
            txw[l] = copysignf(th, x);
            asm volatile("s_waitcnt lgkmcnt(0)" ::: "memory");  // tx write visible
            __builtin_amdgcn_s_barrier();
            __builtin_amdgcn_sched_barrier(0);  // don't hoist next step's ds_reads
        }
        {
            // Flush phase-A x history (steps sA..sA+3), channel l.
            float* xp = Xout + (((size_t)(sA >> 10) << 8) + l) * 1024 + (sA & 1023);
            *(float4*)xp = make_float4(xh[0], xh[1], xh[2], xh[3]);
        }

        // ----- phase B: steps sB..sB+3 using ub; prefetch ua for next iter -----
        {
            const int sN = sB + BATCH;
            const float* p = Up + (((size_t)(sN >> 10) << 8) + l) * 1024 + (sN & 1023);
            float4 v = *(const float4*)p;
            ua[0] = v.x; ua[1] = v.y; ua[2] = v.z; ua[3] = v.w;
        }
#pragma unroll
        for (int sub = 0; sub < BATCH; ++sub) {
            const float4* txp = (const float4*)((sub & 1) ? tx1 : tx0);
            float*        txw = (sub & 1) ? tx0 : tx1;
            float a0 = 0.f, a1 = 0.f, a2 = 0.f, a3 = 0.f;
#pragma unroll
            for (int k = 0; k < 64; ++k) {
                const float4 t = txp[k];
                a0 = fmaf(w[4 * k + 0], t.x, a0);
                a1 = fmaf(w[4 * k + 1], t.y, a1);
                a2 = fmaf(w[4 * k + 2], t.z, a2);
                a3 = fmaf(w[4 * k + 3], t.w, a3);
            }
            const float sum = (a0 + a1) + (a2 + a3);
            const float inp = sum + ub[sub];
            x = fmaf(dt, inp - x, x);
            xh[sub] = x;
            const float av = fabsf(x);
            const float e  = __expf(-2.f * av);
            const float th = (1.f - e) * __fdividef(1.f, 1.f + e);
            txw[l] = copysignf(th, x);
            asm volatile("s_waitcnt lgkmcnt(0)" ::: "memory");
            __builtin_amdgcn_s_barrier();
            __builtin_amdgcn_sched_barrier(0);
        }
        {
            float* xp = Xout + (((size_t)(sB >> 10) << 8) + l) * 1024 + (sB & 1023);
            *(float4*)xp = make_float4(xh[0], xh[1], xh[2], xh[3]);
        }
    }
}

// ---------------------------------------------------------------------------
extern "C" void kernel_launch(void* const* d_in, const int* in_sizes, int n_in,
                              void* d_out, int out_size, void* d_ws, size_t ws_size,
                              hipStream_t stream) {
    const float* u  = (const float*)d_in[0];
    const float* dt = (const float*)d_in[1];
    const float* W  = (const float*)d_in[2];
    const float* M  = (const float*)d_in[3];
    const float* H  = (const float*)d_in[4];
    const float* b  = (const float*)d_in[5];

    float* out0 = (float*)d_out;                        // outputs region (Y)
    float* out1 = out0 + (size_t)IQ * C_CH * T_SEQ;     // membrane region (X)

    dim3 ggrid(T_SEQ / 64, C_CH / 64, IQ);

    // 1) Uproj[iq][c][t] = M @ u_iq  -> staged in out0 (overwritten by Y later)
    gemm_ct<false><<<ggrid, 256, 0, stream>>>(M, u, nullptr, out0);

    // 2) Sequential scan over 65536 steps; writes membrane potentials to out1
    scan_kernel<<<1, 256, 0, stream>>>(W, out0, dt, out1);

    // 3) Y[iq][c][t] = sigmoid(H @ X_iq + b) -> out0
    gemm_ct<true><<<ggrid, 256, 0, stream>>>(H, out1, b, out0);
}

// Round 3
// 49133.655 us; speedup vs baseline: 4.3396x; 4.3396x over previous
//
#include <hip/hip_runtime.h>
#include <math.h>

#define IQ     64
#define C_CH   256
#define T_SEQ  1024
#define NSTEP  (IQ * T_SEQ)
#define BATCH  4   // steps per register batch (u prefetch / x writeback granularity)

typedef _Float16 h2 __attribute__((ext_vector_type(2)));
typedef _Float16 h8 __attribute__((ext_vector_type(8)));

#if defined(__has_builtin)
#if __has_builtin(__builtin_amdgcn_fdot2)
#define HAVE_FDOT2 1
#endif
#endif

#ifdef HAVE_FDOT2
#define FDOT2(a, b, c) __builtin_amdgcn_fdot2((a), (b), (c), false)
#else
static __device__ __forceinline__ float FDOT2(h2 a, h2 b, float c) {
    return fmaf((float)a.x, (float)b.x, fmaf((float)a.y, (float)b.y, c));
}
#endif

// ---------------------------------------------------------------------------
// GEMM in [iq][c][t] layout:
//   Out[iq][c][t] = act( sum_j A[c][j] * In[iq][j][t] (+ bias[c]) )
// Tiles: 64 c x 64 t per block, K staged in chunks of 64. 256 threads.
// Used for (A=M, In=u)  -> Uproj   (no activation)
// and      (A=H, In=X)  -> Y       (sigmoid + bias)
// ---------------------------------------------------------------------------
template <bool SIG>
__global__ void __launch_bounds__(256) gemm_ct(const float* __restrict__ A,
                                               const float* __restrict__ In,
                                               const float* __restrict__ bias,
                                               float* __restrict__ Out) {
    __shared__ float aT[64][65];  // [jj][c]  (A transposed tile, padded)
    __shared__ float bI[64][68];  // [jj][t]  (In tile, padded, 16B-aligned rows)

    const int tid = threadIdx.x;
    const int t0  = blockIdx.x * 64;
    const int c0  = blockIdx.y * 64;
    const int iq  = blockIdx.z;

    const int tt = tid & 15;   // t-quad index (compute mapping)
    const int cc = tid >> 4;   // c-quad index
    const int lr = tid >> 2;   // row for loads
    const int lq = tid & 3;    // quad-column for loads

    float acc[4][4];
#pragma unroll
    for (int m = 0; m < 4; ++m)
#pragma unroll
        for (int n = 0; n < 4; ++n) acc[m][n] = 0.f;

    for (int kc = 0; kc < 4; ++kc) {
        const float* Ar = A + (size_t)(c0 + lr) * 256 + kc * 64;
#pragma unroll
        for (int k2 = 0; k2 < 4; ++k2) {
            float4 v = *(const float4*)(Ar + lq * 4 + k2 * 16);
            int jj = lq * 4 + k2 * 16;
            aT[jj + 0][lr] = v.x;
            aT[jj + 1][lr] = v.y;
            aT[jj + 2][lr] = v.z;
            aT[jj + 3][lr] = v.w;
        }
        const float* Ir = In + ((size_t)iq * 256 + kc * 64 + lr) * 1024 + t0;
#pragma unroll
        for (int k2 = 0; k2 < 4; ++k2) {
            float4 v = *(const float4*)(Ir + lq * 4 + k2 * 16);
            *(float4*)&bI[lr][lq * 4 + k2 * 16] = v;
        }
        __syncthreads();

#pragma unroll 8
        for (int jj = 0; jj < 64; ++jj) {
            const float a0 = aT[jj][cc * 4 + 0];
            const float a1 = aT[jj][cc * 4 + 1];
            const float a2 = aT[jj][cc * 4 + 2];
            const float a3 = aT[jj][cc * 4 + 3];
            const float4 b4 = *(const float4*)&bI[jj][tt * 4];
            acc[0][0] = fmaf(a0, b4.x, acc[0][0]);
            acc[0][1] = fmaf(a0, b4.y, acc[0][1]);
            acc[0][2] = fmaf(a0, b4.z, acc[0][2]);
            acc[0][3] = fmaf(a0, b4.w, acc[0][3]);
            acc[1][0] = fmaf(a1, b4.x, acc[1][0]);
            acc[1][1] = fmaf(a1, b4.y, acc[1][1]);
            acc[1][2] = fmaf(a1, b4.z, acc[1][2]);
            acc[1][3] = fmaf(a1, b4.w, acc[1][3]);
            acc[2][0] = fmaf(a2, b4.x, acc[2][0]);
            acc[2][1] = fmaf(a2, b4.y, acc[2][1]);
            acc[2][2] = fmaf(a2, b4.z, acc[2][2]);
            acc[2][3] = fmaf(a2, b4.w, acc[2][3]);
            acc[3][0] = fmaf(a3, b4.x, acc[3][0]);
            acc[3][1] = fmaf(a3, b4.y, acc[3][1]);
            acc[3][2] = fmaf(a3, b4.z, acc[3][2]);
            acc[3][3] = fmaf(a3, b4.w, acc[3][3]);
        }
        __syncthreads();
    }

#pragma unroll
    for (int m = 0; m < 4; ++m) {
        const int c = c0 + cc * 4 + m;
        float4 v;
        if constexpr (SIG) {
            const float bb = bias[c];
            v.x = __fdividef(1.f, 1.f + __expf(-(acc[m][0] + bb)));
            v.y = __fdividef(1.f, 1.f + __expf(-(acc[m][1] + bb)));
            v.z = __fdividef(1.f, 1.f + __expf(-(acc[m][2] + bb)));
            v.w = __fdividef(1.f, 1.f + __expf(-(acc[m][3] + bb)));
        } else {
            v.x = acc[m][0];
            v.y = acc[m][1];
            v.z = acc[m][2];
            v.w = acc[m][3];
        }
        *(float4*)(Out + ((size_t)iq * 256 + c) * 1024 + t0 + tt * 4) = v;
    }
}

// ---------------------------------------------------------------------------
// Sequential scan: 256 threads (4 waves), 1 channel per lane.
//   - W row as 128 packed-fp16 pairs in VGPRs (128 regs, NO spill; round-2's
//     f32 w[256] + overhead exceeded the 256-VGPR cap and spilled to scratch).
//   - Matvec: 128 x v_dot2_f32_f16 (2 MACs/instr, f32 accumulate).
//   - tanh(x) exchanged as packed fp16 via double-buffered LDS:
//     32 wave-uniform ds_read_b128 per lane-step (broadcast, conflict-free).
//   - ONE raw barrier per step (s_waitcnt lgkmcnt(0) + s_barrier) so vmem
//     prefetch/writeback stays in flight across steps.
// ---------------------------------------------------------------------------
__global__ void __launch_bounds__(256, 1) scan_kernel(const float* __restrict__ W,
                                                      const float* __restrict__ Up,
                                                      const float* __restrict__ dtp,
                                                      float* __restrict__ Xout) {
    __shared__ __align__(16) _Float16 tx0[C_CH];  // tanh(x), parity-0
    __shared__ __align__(16) _Float16 tx1[C_CH];  // tanh(x), parity-1

    const int l = threadIdx.x;   // lane == channel
    const float dt = *dtp;

    // Preload W row for this channel as packed fp16 (128 VGPRs).
    h2 w2[128];
    {
        const float* Wr = W + (size_t)l * 256;
#pragma unroll
        for (int k = 0; k < 64; ++k) {
            float4 v = *(const float4*)(Wr + 4 * k);
            h2 p0, p1;
            p0.x = (_Float16)v.x; p0.y = (_Float16)v.y;
            p1.x = (_Float16)v.z; p1.y = (_Float16)v.w;
            w2[2 * k + 0] = p0;
            w2[2 * k + 1] = p1;
        }
    }

    float x = 0.f;
    tx0[l] = (_Float16)0.f;  // tanh(x0) = 0
    __syncthreads();

    float ua[BATCH], ub[BATCH], xh[BATCH];

    // Preload u batch 0 (steps 0..3).
    {
        float4 v = *(const float4*)(Up + (size_t)l * 1024);
        ua[0] = v.x; ua[1] = v.y; ua[2] = v.z; ua[3] = v.w;
    }

    // One step: matvec via dot2 + state update + tanh + LDS publish + barrier.
    auto do_step = [&](float uin, const _Float16* txr, _Float16* txw) {
        const h8* t8 = (const h8*)txr;
        float acc[8];
#pragma unroll
        for (int j = 0; j < 8; ++j) acc[j] = 0.f;
#pragma unroll
        for (int k = 0; k < 32; ++k) {
            union { h8 v; h2 p[4]; } t;
            t.v = t8[k];  // wave-uniform ds_read_b128 (broadcast)
            const int b = (k & 1) * 4;
            acc[b + 0] = FDOT2(w2[4 * k + 0], t.p[0], acc[b + 0]);
            acc[b + 1] = FDOT2(w2[4 * k + 1], t.p[1], acc[b + 1]);
            acc[b + 2] = FDOT2(w2[4 * k + 2], t.p[2], acc[b + 2]);
            acc[b + 3] = FDOT2(w2[4 * k + 3], t.p[3], acc[b + 3]);
        }
        const float sum = ((acc[0] + acc[1]) + (acc[2] + acc[3])) +
                          ((acc[4] + acc[5]) + (acc[6] + acc[7]));
        const float inp = sum + uin;
        x = fmaf(dt, inp - x, x);  // x + dt*(-x + inp)
        const float av = fabsf(x);
        const float e  = __expf(-2.f * av);
        const float th = (1.f - e) * __fdividef(1.f, 1.f + e);
        txw[l] = (_Float16)copysignf(th, x);
        asm volatile("s_waitcnt lgkmcnt(0)" ::: "memory");  // tx write visible
        __builtin_amdgcn_s_barrier();
        __builtin_amdgcn_sched_barrier(0);  // don't hoist next step's ds_reads
    };

    // One macro-iteration = 2 batches (ping-pong ua/ub) = 8 steps.
#pragma unroll 1
    for (int it = 0; it < NSTEP / (2 * BATCH); ++it) {
        const int sA = it * 2 * BATCH;          // phase A start step
        const int sB = sA + BATCH;              // phase B start step

        // ----- phase A: steps sA..sA+3 using ua; prefetch ub for sB -----
        {
            const float* p = Up + (((size_t)(sB >> 10) << 8) + l) * 1024 + (sB & 1023);
            float4 v = *(const float4*)p;
            ub[0] = v.x; ub[1] = v.y; ub[2] = v.z; ub[3] = v.w;
        }
        do_step(ua[0], tx0, tx1);
        do_step(ua[1], tx1, tx0);
        do_step(ua[2], tx0, tx1);
        do_step(ua[3], tx1, tx0);
        xh[0] = 0.f;  // (placeholder; xh filled below via x tracking)
        // Flush phase-A x history: we need x after each sub-step; re-derive by
        // storing inside do_step is cleaner — but x history was captured there.
        // (xh writes handled below — see note.)
        (void)xh;
        {
            // x history: do_step updated x in-place; capture per-step values.
        }

        // ----- phase B -----
        {
            const int sN = sB + BATCH;
            const float* p = Up + (((size_t)(sN >> 10) << 8) + l) * 1024 + (sN & 1023);
            float4 v = *(const float4*)p;
            ua[0] = v.x; ua[1] = v.y; ua[2] = v.z; ua[3] = v.w;
        }
        do_step(ub[0], tx0, tx1);
        do_step(ub[1], tx1, tx0);
        do_step(ub[2], tx0, tx1);
        do_step(ub[3], tx1, tx0);
    }
}

// NOTE: the lambda-based variant above lost the x-history writeback; the real
// kernel below is the corrected full implementation actually launched.
__global__ void __launch_bounds__(256, 1) scan_kernel2(const float* __restrict__ W,
                                                       const float* __restrict__ Up,
                                                       const float* __restrict__ dtp,
                                                       float* __restrict__ Xout) {
    __shared__ __align__(16) _Float16 tx0[C_CH];
    __shared__ __align__(16) _Float16 tx1[C_CH];

    const int l = threadIdx.x;
    const float dt = *dtp;

    h2 w2[128];
    {
        const float* Wr = W + (size_t)l * 256;
#pragma unroll
        for (int k = 0; k < 64; ++k) {
            float4 v = *(const float4*)(Wr + 4 * k);
            h2 p0, p1;
            p0.x = (_Float16)v.x; p0.y = (_Float16)v.y;
            p1.x = (_Float16)v.z; p1.y = (_Float16)v.w;
            w2[2 * k + 0] = p0;
            w2[2 * k + 1] = p1;
        }
    }

    float x = 0.f;
    tx0[l] = (_Float16)0.f;
    __syncthreads();

    float ua[BATCH], ub[BATCH], xh[BATCH];
    {
        float4 v = *(const float4*)(Up + (size_t)l * 1024);
        ua[0] = v.x; ua[1] = v.y; ua[2] = v.z; ua[3] = v.w;
    }

    auto do_step = [&](float uin, const _Float16* txr, _Float16* txw) -> float {
        const h8* t8 = (const h8*)txr;
        float acc[8];
#pragma unroll
        for (int j = 0; j < 8; ++j) acc[j] = 0.f;
#pragma unroll
        for (int k = 0; k < 32; ++k) {
            union { h8 v; h2 p[4]; } t;
            t.v = t8[k];
            const int b = (k & 1) * 4;
            acc[b + 0] = FDOT2(w2[4 * k + 0], t.p[0], acc[b + 0]);
            acc[b + 1] = FDOT2(w2[4 * k + 1], t.p[1], acc[b + 1]);
            acc[b + 2] = FDOT2(w2[4 * k + 2], t.p[2], acc[b + 2]);
            acc[b + 3] = FDOT2(w2[4 * k + 3], t.p[3], acc[b + 3]);
        }
        const float sum = ((acc[0] + acc[1]) + (acc[2] + acc[3])) +
                          ((acc[4] + acc[5]) + (acc[6] + acc[7]));
        const float inp = sum + uin;
        x = fmaf(dt, inp - x, x);
        const float av = fabsf(x);
        const float e  = __expf(-2.f * av);
        const float th = (1.f - e) * __fdividef(1.f, 1.f + e);
        txw[l] = (_Float16)copysignf(th, x);
        asm volatile("s_waitcnt lgkmcnt(0)" ::: "memory");
        __builtin_amdgcn_s_barrier();
        __builtin_amdgcn_sched_barrier(0);
        return x;
    };

#pragma unroll 1
    for (int it = 0; it < NSTEP / (2 * BATCH); ++it) {
        const int sA = it * 2 * BATCH;
        const int sB = sA + BATCH;

        {
            const float* p = Up + (((size_t)(sB >> 10) << 8) + l) * 1024 + (sB & 1023);
            float4 v = *(const float4*)p;
            ub[0] = v.x; ub[1] = v.y; ub[2] = v.z; ub[3] = v.w;
        }
        xh[0] = do_step(ua[0], tx0, tx1);
        xh[1] = do_step(ua[1], tx1, tx0);
        xh[2] = do_step(ua[2], tx0, tx1);
        xh[3] = do_step(ua[3], tx1, tx0);
        {
            float* xp = Xout + (((size_t)(sA >> 10) << 8) + l) * 1024 + (sA & 1023);
            *(float4*)xp = make_float4(xh[0], xh[1], xh[2], xh[3]);
        }

        {
            const int sN = sB + BATCH;
            const float* p = Up + (((size_t)(sN >> 10) << 8) + l) * 1024 + (sN & 1023);
            float4 v = *(const float4*)p;
            ua[0] = v.x; ua[1] = v.y; ua[2] = v.z; ua[3] = v.w;
        }
        xh[0] = do_step(ub[0], tx0, tx1);
        xh[1] = do_step(ub[1], tx1, tx0);
        xh[2] = do_step(ub[2], tx0, tx1);
        xh[3] = do_step(ub[3], tx1, tx0);
        {
            float* xp = Xout + (((size_t)(sB >> 10) << 8) + l) * 1024 + (sB & 1023);
            *(float4*)xp = make_float4(xh[0], xh[1], xh[2], xh[3]);
        }
    }
}

// ---------------------------------------------------------------------------
extern "C" void kernel_launch(void* const* d_in, const int* in_sizes, int n_in,
                              void* d_out, int out_size, void* d_ws, size_t ws_size,
                              hipStream_t stream) {
    const float* u  = (const float*)d_in[0];
    const float* dt = (const float*)d_in[1];
    const float* W  = (const float*)d_in[2];
    const float* M  = (const float*)d_in[3];
    const float* H  = (const float*)d_in[4];
    const float* b  = (const float*)d_in[5];

    float* out0 = (float*)d_out;                        // outputs region (Y)
    float* out1 = out0 + (size_t)IQ * C_CH * T_SEQ;     // membrane region (X)

    dim3 ggrid(T_SEQ / 64, C_CH / 64, IQ);

    // 1) Uproj[iq][c][t] = M @ u_iq  -> staged in out0 (overwritten by Y later)
    gemm_ct<false><<<ggrid, 256, 0, stream>>>(M, u, nullptr, out0);

    // 2) Sequential scan over 65536 steps; writes membrane potentials to out1
    scan_kernel2<<<1, 256, 0, stream>>>(W, out0, dt, out1);

    // 3) Y[iq][c][t] = sigmoid(H @ X_iq + b) -> out0
    gemm_ct<true><<<ggrid, 256, 0, stream>>>(H, out1, b, out0);
}

// Round 4
// 28086.517 us; speedup vs baseline: 7.5916x; 1.7494x over previous
//
#include <hip/hip_runtime.h>
#include <math.h>

#define IQ     64
#define C_CH   256
#define T_SEQ  1024
#define NSTEP  (IQ * T_SEQ)
#define BATCH  4   // steps per register batch (u prefetch / x writeback granularity)

typedef _Float16 h8v __attribute__((ext_vector_type(8)));
typedef float    f4v __attribute__((ext_vector_type(4)));

// ---------------------------------------------------------------------------
// GEMM in [iq][c][t] layout (unchanged from round 1; ~180us total both calls):
//   Out[iq][c][t] = act( sum_j A[c][j] * In[iq][j][t] (+ bias[c]) )
// ---------------------------------------------------------------------------
template <bool SIG>
__global__ void __launch_bounds__(256) gemm_ct(const float* __restrict__ A,
                                               const float* __restrict__ In,
                                               const float* __restrict__ bias,
                                               float* __restrict__ Out) {
    __shared__ float aT[64][65];
    __shared__ float bI[64][68];

    const int tid = threadIdx.x;
    const int t0  = blockIdx.x * 64;
    const int c0  = blockIdx.y * 64;
    const int iq  = blockIdx.z;

    const int tt = tid & 15;
    const int cc = tid >> 4;
    const int lr = tid >> 2;
    const int lq = tid & 3;

    float acc[4][4];
#pragma unroll
    for (int m = 0; m < 4; ++m)
#pragma unroll
        for (int n = 0; n < 4; ++n) acc[m][n] = 0.f;

    for (int kc = 0; kc < 4; ++kc) {
        const float* Ar = A + (size_t)(c0 + lr) * 256 + kc * 64;
#pragma unroll
        for (int k2 = 0; k2 < 4; ++k2) {
            float4 v = *(const float4*)(Ar + lq * 4 + k2 * 16);
            int jj = lq * 4 + k2 * 16;
            aT[jj + 0][lr] = v.x;
            aT[jj + 1][lr] = v.y;
            aT[jj + 2][lr] = v.z;
            aT[jj + 3][lr] = v.w;
        }
        const float* Ir = In + ((size_t)iq * 256 + kc * 64 + lr) * 1024 + t0;
#pragma unroll
        for (int k2 = 0; k2 < 4; ++k2) {
            float4 v = *(const float4*)(Ir + lq * 4 + k2 * 16);
            *(float4*)&bI[lr][lq * 4 + k2 * 16] = v;
        }
        __syncthreads();

#pragma unroll 8
        for (int jj = 0; jj < 64; ++jj) {
            const float a0 = aT[jj][cc * 4 + 0];
            const float a1 = aT[jj][cc * 4 + 1];
            const float a2 = aT[jj][cc * 4 + 2];
            const float a3 = aT[jj][cc * 4 + 3];
            const float4 b4 = *(const float4*)&bI[jj][tt * 4];
            acc[0][0] = fmaf(a0, b4.x, acc[0][0]);
            acc[0][1] = fmaf(a0, b4.y, acc[0][1]);
            acc[0][2] = fmaf(a0, b4.z, acc[0][2]);
            acc[0][3] = fmaf(a0, b4.w, acc[0][3]);
            acc[1][0] = fmaf(a1, b4.x, acc[1][0]);
            acc[1][1] = fmaf(a1, b4.y, acc[1][1]);
            acc[1][2] = fmaf(a1, b4.z, acc[1][2]);
            acc[1][3] = fmaf(a1, b4.w, acc[1][3]);
            acc[2][0] = fmaf(a2, b4.x, acc[2][0]);
            acc[2][1] = fmaf(a2, b4.y, acc[2][1]);
            acc[2][2] = fmaf(a2, b4.z, acc[2][2]);
            acc[2][3] = fmaf(a2, b4.w, acc[2][3]);
            acc[3][0] = fmaf(a3, b4.x, acc[3][0]);
            acc[3][1] = fmaf(a3, b4.y, acc[3][1]);
            acc[3][2] = fmaf(a3, b4.z, acc[3][2]);
            acc[3][3] = fmaf(a3, b4.w, acc[3][3]);
        }
        __syncthreads();
    }

#pragma unroll
    for (int m = 0; m < 4; ++m) {
        const int c = c0 + cc * 4 + m;
        float4 v;
        if constexpr (SIG) {
            const float bb = bias[c];
            v.x = __fdividef(1.f, 1.f + __expf(-(acc[m][0] + bb)));
            v.y = __fdividef(1.f, 1.f + __expf(-(acc[m][1] + bb)));
            v.z = __fdividef(1.f, 1.f + __expf(-(acc[m][2] + bb)));
            v.w = __fdividef(1.f, 1.f + __expf(-(acc[m][3] + bb)));
        } else {
            v.x = acc[m][0];
            v.y = acc[m][1];
            v.z = acc[m][2];
            v.w = acc[m][3];
        }
        *(float4*)(Out + ((size_t)iq * 256 + c) * 1024 + t0 + tt * 4) = v;
    }
}

// ---------------------------------------------------------------------------
// Sequential scan via MFMA: 256 threads (4 waves), wave wv owns channels
// [wv*64, wv*64+64).
//   y^T = t^T @ W^T :  A (16x32) = tanh-vector broadcast over rows,
//                      B (32x16) = W^T slice, preloaded fp16 in VGPRs.
//   mfma_f32_16x16x32_f16 fragment layouts (gfx950):
//     A: lane l holds A[i=l%16][k=8*(l/16)+f]  -> t[kt*32+8g+f], g=l>>4
//     B: lane l holds B[k=8*(l/16)+f][j=l%16]  -> W[wv*64+jt*16+q][kt*32+8g+f]
//     C: col j=l&15, rows redundant (A rows equal) -> lane owns channel
//        cidx = wv*64 + g*16 + q via jt=g, y = acc[g].x (3 cndmask select).
//   Per step/wave: 8 ds_read_b128 (vs 32 in round 3's broadcast-dot2 design,
//   which saturated the shared LDS pipe) + 32 MFMA on the wave's own SIMD.
//   One raw barrier per step; u prefetch / x writeback in float4 batches.
// ---------------------------------------------------------------------------
__global__ void __launch_bounds__(256, 1) scan_mfma(const float* __restrict__ W,
                                                    const float* __restrict__ Up,
                                                    const float* __restrict__ dtp,
                                                    float* __restrict__ Xout) {
    __shared__ __align__(16) _Float16 tx0[C_CH];  // tanh(x), parity-0
    __shared__ __align__(16) _Float16 tx1[C_CH];  // tanh(x), parity-1

    const int tid  = threadIdx.x;
    const int lane = tid & 63;
    const int wv   = tid >> 6;   // wave 0..3
    const int g    = lane >> 4;  // 0..3
    const int q    = lane & 15;  // 0..15
    const int cidx = (wv << 6) + (g << 4) + q;  // owned channel
    const float dt = *dtp;

    // Preload W^T fragments (B operand), fp16: 4 j-tiles x 8 k-tiles x 4 VGPRs.
    auto ld8 = [](const float* p) -> h8v {
        float4 a = *(const float4*)p;
        float4 b = *(const float4*)(p + 4);
        h8v r;
        r[0] = (_Float16)a.x; r[1] = (_Float16)a.y;
        r[2] = (_Float16)a.z; r[3] = (_Float16)a.w;
        r[4] = (_Float16)b.x; r[5] = (_Float16)b.y;
        r[6] = (_Float16)b.z; r[7] = (_Float16)b.w;
        return r;
    };
    h8v wB0[8], wB1[8], wB2[8], wB3[8];
    {
        const float* r0 = W + (size_t)(wv * 64 +  0 + q) * 256 + g * 8;
        const float* r1 = W + (size_t)(wv * 64 + 16 + q) * 256 + g * 8;
        const float* r2 = W + (size_t)(wv * 64 + 32 + q) * 256 + g * 8;
        const float* r3 = W + (size_t)(wv * 64 + 48 + q) * 256 + g * 8;
#pragma unroll
        for (int kt = 0; kt < 8; ++kt) {
            wB0[kt] = ld8(r0 + kt * 32);
            wB1[kt] = ld8(r1 + kt * 32);
            wB2[kt] = ld8(r2 + kt * 32);
            wB3[kt] = ld8(r3 + kt * 32);
        }
    }

    float x = 0.f;
    tx0[cidx] = (_Float16)0.f;  // tanh(x0) = 0
    __syncthreads();

    float ua[BATCH], ub[BATCH], xh[BATCH];
    {
        float4 v = *(const float4*)(Up + (size_t)cidx * 1024);
        ua[0] = v.x; ua[1] = v.y; ua[2] = v.z; ua[3] = v.w;
    }

    // One step: MFMA matvec + state update + tanh + LDS publish + raw barrier.
    auto do_step = [&](float uin, const _Float16* txr, _Float16* txw) -> float {
        const h8v* tp = (const h8v*)txr;
        // A fragments: t[kt*32 + 8g .. +7]; 4 distinct 16B addrs per wave.
        h8v a0 = tp[0 * 4 + g], a1 = tp[1 * 4 + g];
        h8v a2 = tp[2 * 4 + g], a3 = tp[3 * 4 + g];
        h8v a4 = tp[4 * 4 + g], a5 = tp[5 * 4 + g];
        h8v a6 = tp[6 * 4 + g], a7 = tp[7 * 4 + g];
        f4v c0 = {0.f, 0.f, 0.f, 0.f};
        f4v c1 = c0, c2 = c0, c3 = c0;
#define STEPK(A, K)                                                     \
        c0 = __builtin_amdgcn_mfma_f32_16x16x32_f16(A, wB0[K], c0, 0, 0, 0); \
        c1 = __builtin_amdgcn_mfma_f32_16x16x32_f16(A, wB1[K], c1, 0, 0, 0); \
        c2 = __builtin_amdgcn_mfma_f32_16x16x32_f16(A, wB2[K], c2, 0, 0, 0); \
        c3 = __builtin_amdgcn_mfma_f32_16x16x32_f16(A, wB3[K], c3, 0, 0, 0);
        STEPK(a0, 0) STEPK(a1, 1) STEPK(a2, 2) STEPK(a3, 3)
        STEPK(a4, 4) STEPK(a5, 5) STEPK(a6, 6) STEPK(a7, 7)
#undef STEPK
        // Lane owns channel of j-tile jt = g; all C rows equal -> take .x.
        const float y01 = (g & 1) ? c1.x : c0.x;
        const float y23 = (g & 1) ? c3.x : c2.x;
        const float y   = (g & 2) ? y23 : y01;
        const float inp = y + uin;
        x = fmaf(dt, inp - x, x);  // x + dt*(-x + inp)
        const float av = fabsf(x);
        const float e  = __expf(-2.f * av);
        const float th = (1.f - e) * __fdividef(1.f, 1.f + e);
        txw[cidx] = (_Float16)copysignf(th, x);
        asm volatile("s_waitcnt lgkmcnt(0)" ::: "memory");  // tx write visible
        __builtin_amdgcn_s_barrier();
        __builtin_amdgcn_sched_barrier(0);  // don't hoist next step's ds_reads
        return x;
    };

    // One macro-iteration = 2 batches (ping-pong ua/ub) = 8 steps.
#pragma unroll 1
    for (int it = 0; it < NSTEP / (2 * BATCH); ++it) {
        const int sA = it * 2 * BATCH;
        const int sB = sA + BATCH;

        {   // prefetch ub for phase B (last-iter overrun lands in out1: unused)
            const float* p = Up + (((size_t)(sB >> 10) << 8) + cidx) * 1024 + (sB & 1023);
            float4 v = *(const float4*)p;
            ub[0] = v.x; ub[1] = v.y; ub[2] = v.z; ub[3] = v.w;
        }
        xh[0] = do_step(ua[0], tx0, tx1);
        xh[1] = do_step(ua[1], tx1, tx0);
        xh[2] = do_step(ua[2], tx0, tx1);
        xh[3] = do_step(ua[3], tx1, tx0);
        {
            float* xp = Xout + (((size_t)(sA >> 10) << 8) + cidx) * 1024 + (sA & 1023);
            *(float4*)xp = make_float4(xh[0], xh[1], xh[2], xh[3]);
        }

        {   // prefetch ua for next macro-iteration
            const int sN = sB + BATCH;
            const float* p = Up + (((size_t)(sN >> 10) << 8) + cidx) * 1024 + (sN & 1023);
            float4 v = *(const float4*)p;
            ua[0] = v.x; ua[1] = v.y; ua[2] = v.z; ua[3] = v.w;
        }
        xh[0] = do_step(ub[0], tx0, tx1);
        xh[1] = do_step(ub[1], tx1, tx0);
        xh[2] = do_step(ub[2], tx0, tx1);
        xh[3] = do_step(ub[3], tx1, tx0);
        {
            float* xp = Xout + (((size_t)(sB >> 10) << 8) + cidx) * 1024 + (sB & 1023);
            *(float4*)xp = make_float4(xh[0], xh[1], xh[2], xh[3]);
        }
    }
}

// ---------------------------------------------------------------------------
extern "C" void kernel_launch(void* const* d_in, const int* in_sizes, int n_in,
                              void* d_out, int out_size, void* d_ws, size_t ws_size,
                              hipStream_t stream) {
    const float* u  = (const float*)d_in[0];
    const float* dt = (const float*)d_in[1];
    const float* W  = (const float*)d_in[2];
    const float* M  = (const float*)d_in[3];
    const float* H  = (const float*)d_in[4];
    const float* b  = (const float*)d_in[5];

    float* out0 = (float*)d_out;                        // outputs region (Y)
    float* out1 = out0 + (size_t)IQ * C_CH * T_SEQ;     // membrane region (X)

    dim3 ggrid(T_SEQ / 64, C_CH / 64, IQ);

    // 1) Uproj[iq][c][t] = M @ u_iq  -> staged in out0 (overwritten by Y later)
    gemm_ct<false><<<ggrid, 256, 0, stream>>>(M, u, nullptr, out0);

    // 2) Sequential scan over 65536 steps; writes membrane potentials to out1
    scan_mfma<<<1, 256, 0, stream>>>(W, out0, dt, out1);

    // 3) Y[iq][c][t] = sigmoid(H @ X_iq + b) -> out0
    gemm_ct<true><<<ggrid, 256, 0, stream>>>(H, out1, b, out0);
}

// Round 5
// 25952.039 us; speedup vs baseline: 8.2160x; 1.0822x over previous
//
#include <hip/hip_runtime.h>
#include <math.h>

#define IQ     64
#define C_CH   256
#define T_SEQ  1024
#define NSTEP  (IQ * T_SEQ)
#define BATCH  4   // steps per register batch (u prefetch / x writeback granularity)

typedef _Float16 h8v __attribute__((ext_vector_type(8)));
typedef float    f4v __attribute__((ext_vector_type(4)));

// ---------------------------------------------------------------------------
// GEMM in [iq][c][t] layout (unchanged; ~180us total for both calls):
//   Out[iq][c][t] = act( sum_j A[c][j] * In[iq][j][t] (+ bias[c]) )
// ---------------------------------------------------------------------------
template <bool SIG>
__global__ void __launch_bounds__(256) gemm_ct(const float* __restrict__ A,
                                               const float* __restrict__ In,
                                               const float* __restrict__ bias,
                                               float* __restrict__ Out) {
    __shared__ float aT[64][65];
    __shared__ float bI[64][68];

    const int tid = threadIdx.x;
    const int t0  = blockIdx.x * 64;
    const int c0  = blockIdx.y * 64;
    const int iq  = blockIdx.z;

    const int tt = tid & 15;
    const int cc = tid >> 4;
    const int lr = tid >> 2;
    const int lq = tid & 3;

    float acc[4][4];
#pragma unroll
    for (int m = 0; m < 4; ++m)
#pragma unroll
        for (int n = 0; n < 4; ++n) acc[m][n] = 0.f;

    for (int kc = 0; kc < 4; ++kc) {
        const float* Ar = A + (size_t)(c0 + lr) * 256 + kc * 64;
#pragma unroll
        for (int k2 = 0; k2 < 4; ++k2) {
            float4 v = *(const float4*)(Ar + lq * 4 + k2 * 16);
            int jj = lq * 4 + k2 * 16;
            aT[jj + 0][lr] = v.x;
            aT[jj + 1][lr] = v.y;
            aT[jj + 2][lr] = v.z;
            aT[jj + 3][lr] = v.w;
        }
        const float* Ir = In + ((size_t)iq * 256 + kc * 64 + lr) * 1024 + t0;
#pragma unroll
        for (int k2 = 0; k2 < 4; ++k2) {
            float4 v = *(const float4*)(Ir + lq * 4 + k2 * 16);
            *(float4*)&bI[lr][lq * 4 + k2 * 16] = v;
        }
        __syncthreads();

#pragma unroll 8
        for (int jj = 0; jj < 64; ++jj) {
            const float a0 = aT[jj][cc * 4 + 0];
            const float a1 = aT[jj][cc * 4 + 1];
            const float a2 = aT[jj][cc * 4 + 2];
            const float a3 = aT[jj][cc * 4 + 3];
            const float4 b4 = *(const float4*)&bI[jj][tt * 4];
            acc[0][0] = fmaf(a0, b4.x, acc[0][0]);
            acc[0][1] = fmaf(a0, b4.y, acc[0][1]);
            acc[0][2] = fmaf(a0, b4.z, acc[0][2]);
            acc[0][3] = fmaf(a0, b4.w, acc[0][3]);
            acc[1][0] = fmaf(a1, b4.x, acc[1][0]);
            acc[1][1] = fmaf(a1, b4.y, acc[1][1]);
            acc[1][2] = fmaf(a1, b4.z, acc[1][2]);
            acc[1][3] = fmaf(a1, b4.w, acc[1][3]);
            acc[2][0] = fmaf(a2, b4.x, acc[2][0]);
            acc[2][1] = fmaf(a2, b4.y, acc[2][1]);
            acc[2][2] = fmaf(a2, b4.z, acc[2][2]);
            acc[2][3] = fmaf(a2, b4.w, acc[2][3]);
            acc[3][0] = fmaf(a3, b4.x, acc[3][0]);
            acc[3][1] = fmaf(a3, b4.y, acc[3][1]);
            acc[3][2] = fmaf(a3, b4.z, acc[3][2]);
            acc[3][3] = fmaf(a3, b4.w, acc[3][3]);
        }
        __syncthreads();
    }

#pragma unroll
    for (int m = 0; m < 4; ++m) {
        const int c = c0 + cc * 4 + m;
        float4 v;
        if constexpr (SIG) {
            const float bb = bias[c];
            v.x = __fdividef(1.f, 1.f + __expf(-(acc[m][0] + bb)));
            v.y = __fdividef(1.f, 1.f + __expf(-(acc[m][1] + bb)));
            v.z = __fdividef(1.f, 1.f + __expf(-(acc[m][2] + bb)));
            v.w = __fdividef(1.f, 1.f + __expf(-(acc[m][3] + bb)));
        } else {
            v.x = acc[m][0];
            v.y = acc[m][1];
            v.z = acc[m][2];
            v.w = acc[m][3];
        }
        *(float4*)(Out + ((size_t)iq * 256 + c) * 1024 + t0 + tt * 4) = v;
    }
}

// ---------------------------------------------------------------------------
// Sequential scan via MFMA, 8 waves (512 threads) = 2 waves per SIMD.
//   Wave wv owns channels [wv*32, wv*32+32): 2 j-tiles x 8 k-tiles
//   = 16 x mfma_f32_16x16x32_f16 per step. Per-SIMD matrix-pipe time per
//   step is unchanged (~620 cyc = 32 instr x ~19.4 cyc/SIMD), but each
//   wave's serial tail (post-barrier ds_read latency, tanh, barrier wait)
//   hides under the sibling wave's MFMAs.
//   Fragments (verified round 4, absmax 0.0078):
//     A: lane l holds t[kt*32 + 8g + f], g=l>>4, f=0..7 (broadcast rows)
//     B: lane l holds W[cb + jt*16 + q][kt*32 + 8g + f], q=l&15
//     C: col j=q -> channel cb + jt*16 + q; rows redundant -> .x
//   2 accumulator chains per j-tile (dep distance 4 instr). All lanes
//   redundantly update channel (g&1 selects j-tile); lanes g<2 own the
//   tx publish and global x writeback. One raw barrier per step.
// ---------------------------------------------------------------------------
__global__ void __launch_bounds__(512, 1) scan_mfma8(const float* __restrict__ W,
                                                     const float* __restrict__ Up,
                                                     const float* __restrict__ dtp,
                                                     float* __restrict__ Xout) {
    __shared__ __align__(16) _Float16 tx0[C_CH];  // tanh(x), parity-0
    __shared__ __align__(16) _Float16 tx1[C_CH];  // tanh(x), parity-1

    const int tid  = threadIdx.x;
    const int lane = tid & 63;
    const int wv   = tid >> 6;       // wave 0..7
    const int g    = lane >> 4;      // 0..3 (k-slice group)
    const int q    = lane & 15;      // 0..15 (column / channel-within-tile)
    const int cb   = wv << 5;        // wave's channel base
    const int jsel = g & 1;          // which j-tile this lane updates
    const int cown = cb + (jsel << 4) + q;  // updated channel (g2/g3 mirror)
    const bool wr  = (g < 2);        // lanes that publish tx / write x
    const float dt = *dtp;

    // Preload B fragments (W rows for both j-tiles), fp16: 2 x 8 x 4 VGPRs.
    auto ld8 = [](const float* p) -> h8v {
        float4 a = *(const float4*)p;
        float4 b = *(const float4*)(p + 4);
        h8v r;
        r[0] = (_Float16)a.x; r[1] = (_Float16)a.y;
        r[2] = (_Float16)a.z; r[3] = (_Float16)a.w;
        r[4] = (_Float16)b.x; r[5] = (_Float16)b.y;
        r[6] = (_Float16)b.z; r[7] = (_Float16)b.w;
        return r;
    };
    h8v wB0[8], wB1[8];
    {
        const float* r0 = W + (size_t)(cb +  0 + q) * 256 + g * 8;
        const float* r1 = W + (size_t)(cb + 16 + q) * 256 + g * 8;
#pragma unroll
        for (int kt = 0; kt < 8; ++kt) {
            wB0[kt] = ld8(r0 + kt * 32);
            wB1[kt] = ld8(r1 + kt * 32);
        }
    }

    float x = 0.f;
    if (wr) tx0[cown] = (_Float16)0.f;  // covers all 256 channels across waves
    __syncthreads();

    float ua[BATCH], ub[BATCH], xh[BATCH];
    {
        float4 v = *(const float4*)(Up + (size_t)cown * 1024);
        ua[0] = v.x; ua[1] = v.y; ua[2] = v.z; ua[3] = v.w;
    }

    // One step: 16 MFMA + state update + tanh + LDS publish + raw barrier.
    auto do_step = [&](float uin, const _Float16* txr, _Float16* txw) -> float {
        const h8v* tp = (const h8v*)txr;
        // A fragments: t[kt*32 + 8g .. +7]; 4 distinct 16B addrs per wave.
        h8v a0 = tp[0 * 4 + g], a1 = tp[1 * 4 + g];
        h8v a2 = tp[2 * 4 + g], a3 = tp[3 * 4 + g];
        h8v a4 = tp[4 * 4 + g], a5 = tp[5 * 4 + g];
        h8v a6 = tp[6 * 4 + g], a7 = tp[7 * 4 + g];
        f4v c00 = {0.f, 0.f, 0.f, 0.f};   // j-tile 0, even kt
        f4v c01 = c00;                     // j-tile 0, odd kt
        f4v c10 = c00;                     // j-tile 1, even kt
        f4v c11 = c00;                     // j-tile 1, odd kt
        c00 = __builtin_amdgcn_mfma_f32_16x16x32_f16(a0, wB0[0], c00, 0, 0, 0);
        c10 = __builtin_amdgcn_mfma_f32_16x16x32_f16(a0, wB1[0], c10, 0, 0, 0);
        c01 = __builtin_amdgcn_mfma_f32_16x16x32_f16(a1, wB0[1], c01, 0, 0, 0);
        c11 = __builtin_amdgcn_mfma_f32_16x16x32_f16(a1, wB1[1], c11, 0, 0, 0);
        c00 = __builtin_amdgcn_mfma_f32_16x16x32_f16(a2, wB0[2], c00, 0, 0, 0);
        c10 = __builtin_amdgcn_mfma_f32_16x16x32_f16(a2, wB1[2], c10, 0, 0, 0);
        c01 = __builtin_amdgcn_mfma_f32_16x16x32_f16(a3, wB0[3], c01, 0, 0, 0);
        c11 = __builtin_amdgcn_mfma_f32_16x16x32_f16(a3, wB1[3], c11, 0, 0, 0);
        c00 = __builtin_amdgcn_mfma_f32_16x16x32_f16(a4, wB0[4], c00, 0, 0, 0);
        c10 = __builtin_amdgcn_mfma_f32_16x16x32_f16(a4, wB1[4], c10, 0, 0, 0);
        c01 = __builtin_amdgcn_mfma_f32_16x16x32_f16(a5, wB0[5], c01, 0, 0, 0);
        c11 = __builtin_amdgcn_mfma_f32_16x16x32_f16(a5, wB1[5], c11, 0, 0, 0);
        c00 = __builtin_amdgcn_mfma_f32_16x16x32_f16(a6, wB0[6], c00, 0, 0, 0);
        c10 = __builtin_amdgcn_mfma_f32_16x16x32_f16(a6, wB1[6], c10, 0, 0, 0);
        c01 = __builtin_amdgcn_mfma_f32_16x16x32_f16(a7, wB0[7], c01, 0, 0, 0);
        c11 = __builtin_amdgcn_mfma_f32_16x16x32_f16(a7, wB1[7], c11, 0, 0, 0);
        const float y0 = c00.x + c01.x;
        const float y1 = c10.x + c11.x;
        const float y  = jsel ? y1 : y0;
        const float inp = y + uin;
        x = fmaf(dt, inp - x, x);  // x + dt*(-x + inp)
        const float av = fabsf(x);
        const float e  = __expf(-2.f * av);
        const float th = (1.f - e) * __fdividef(1.f, 1.f + e);
        if (wr) txw[cown] = (_Float16)copysignf(th, x);
        asm volatile("s_waitcnt lgkmcnt(0)" ::: "memory");  // tx write visible
        __builtin_amdgcn_s_barrier();
        __builtin_amdgcn_sched_barrier(0);  // don't hoist next step's ds_reads
        return x;
    };

    // One macro-iteration = 2 batches (ping-pong ua/ub) = 8 steps.
#pragma unroll 1
    for (int it = 0; it < NSTEP / (2 * BATCH); ++it) {
        const int sA = it * 2 * BATCH;
        const int sB = sA + BATCH;

        {   // prefetch ub for phase B (last-iter overrun lands in out1: unused)
            const float* p = Up + (((size_t)(sB >> 10) << 8) + cown) * 1024 + (sB & 1023);
            float4 v = *(const float4*)p;
            ub[0] = v.x; ub[1] = v.y; ub[2] = v.z; ub[3] = v.w;
        }
        xh[0] = do_step(ua[0], tx0, tx1);
        xh[1] = do_step(ua[1], tx1, tx0);
        xh[2] = do_step(ua[2], tx0, tx1);
        xh[3] = do_step(ua[3], tx1, tx0);
        if (wr) {
            float* xp = Xout + (((size_t)(sA >> 10) << 8) + cown) * 1024 + (sA & 1023);
            *(float4*)xp = make_float4(xh[0], xh[1], xh[2], xh[3]);
        }

        {   // prefetch ua for next macro-iteration
            const int sN = sB + BATCH;
            const float* p = Up + (((size_t)(sN >> 10) << 8) + cown) * 1024 + (sN & 1023);
            float4 v = *(const float4*)p;
            ua[0] = v.x; ua[1] = v.y; ua[2] = v.z; ua[3] = v.w;
        }
        xh[0] = do_step(ub[0], tx0, tx1);
        xh[1] = do_step(ub[1], tx1, tx0);
        xh[2] = do_step(ub[2], tx0, tx1);
        xh[3] = do_step(ub[3], tx1, tx0);
        if (wr) {
            float* xp = Xout + (((size_t)(sB >> 10) << 8) + cown) * 1024 + (sB & 1023);
            *(float4*)xp = make_float4(xh[0], xh[1], xh[2], xh[3]);
        }
    }
}

// ---------------------------------------------------------------------------
extern "C" void kernel_launch(void* const* d_in, const int* in_sizes, int n_in,
                              void* d_out, int out_size, void* d_ws, size_t ws_size,
                              hipStream_t stream) {
    const float* u  = (const float*)d_in[0];
    const float* dt = (const float*)d_in[1];
    const float* W  = (const float*)d_in[2];
    const float* M  = (const float*)d_in[3];
    const float* H  = (const float*)d_in[4];
    const float* b  = (const float*)d_in[5];

    float* out0 = (float*)d_out;                        // outputs region (Y)
    float* out1 = out0 + (size_t)IQ * C_CH * T_SEQ;     // membrane region (X)

    dim3 ggrid(T_SEQ / 64, C_CH / 64, IQ);

    // 1) Uproj[iq][c][t] = M @ u_iq  -> staged in out0 (overwritten by Y later)
    gemm_ct<false><<<ggrid, 256, 0, stream>>>(M, u, nullptr, out0);

    // 2) Sequential scan over 65536 steps; writes membrane potentials to out1
    scan_mfma8<<<1, 512, 0, stream>>>(W, out0, dt, out1);

    // 3) Y[iq][c][t] = sigmoid(H @ X_iq + b) -> out0
    gemm_ct<true><<<ggrid, 256, 0, stream>>>(H, out1, b, out0);
}

// Round 6
// 23310.025 us; speedup vs baseline: 9.1473x; 1.1133x over previous
//
#include <hip/hip_runtime.h>
#include <math.h>

#define IQ     64
#define C_CH   256
#define T_SEQ  1024
#define NSTEP  (IQ * T_SEQ)
#define BLK    16   // steps per Picard block (= MFMA rows)
#define MITER  4    // Picard iterations per block

typedef _Float16 h8v __attribute__((ext_vector_type(8)));
typedef _Float16 h4v __attribute__((ext_vector_type(4)));
typedef float    f4v __attribute__((ext_vector_type(4)));

// ---------------------------------------------------------------------------
// GEMM in [iq][c][t] layout (unchanged):
//   Out[iq][c][t] = act( sum_j A[c][j] * In[iq][j][t] (+ bias[c]) )
// ---------------------------------------------------------------------------
template <bool SIG>
__global__ void __launch_bounds__(256) gemm_ct(const float* __restrict__ A,
                                               const float* __restrict__ In,
                                               const float* __restrict__ bias,
                                               float* __restrict__ Out) {
    __shared__ float aT[64][65];
    __shared__ float bI[64][68];

    const int tid = threadIdx.x;
    const int t0  = blockIdx.x * 64;
    const int c0  = blockIdx.y * 64;
    const int iq  = blockIdx.z;

    const int tt = tid & 15;
    const int cc = tid >> 4;
    const int lr = tid >> 2;
    const int lq = tid & 3;

    float acc[4][4];
#pragma unroll
    for (int m = 0; m < 4; ++m)
#pragma unroll
        for (int n = 0; n < 4; ++n) acc[m][n] = 0.f;

    for (int kc = 0; kc < 4; ++kc) {
        const float* Ar = A + (size_t)(c0 + lr) * 256 + kc * 64;
#pragma unroll
        for (int k2 = 0; k2 < 4; ++k2) {
            float4 v = *(const float4*)(Ar + lq * 4 + k2 * 16);
            int jj = lq * 4 + k2 * 16;
            aT[jj + 0][lr] = v.x;
            aT[jj + 1][lr] = v.y;
            aT[jj + 2][lr] = v.z;
            aT[jj + 3][lr] = v.w;
        }
        const float* Ir = In + ((size_t)iq * 256 + kc * 64 + lr) * 1024 + t0;
#pragma unroll
        for (int k2 = 0; k2 < 4; ++k2) {
            float4 v = *(const float4*)(Ir + lq * 4 + k2 * 16);
            *(float4*)&bI[lr][lq * 4 + k2 * 16] = v;
        }
        __syncthreads();

#pragma unroll 8
        for (int jj = 0; jj < 64; ++jj) {
            const float a0 = aT[jj][cc * 4 + 0];
            const float a1 = aT[jj][cc * 4 + 1];
            const float a2 = aT[jj][cc * 4 + 2];
            const float a3 = aT[jj][cc * 4 + 3];
            const float4 b4 = *(const float4*)&bI[jj][tt * 4];
            acc[0][0] = fmaf(a0, b4.x, acc[0][0]);
            acc[0][1] = fmaf(a0, b4.y, acc[0][1]);
            acc[0][2] = fmaf(a0, b4.z, acc[0][2]);
            acc[0][3] = fmaf(a0, b4.w, acc[0][3]);
            acc[1][0] = fmaf(a1, b4.x, acc[1][0]);
            acc[1][1] = fmaf(a1, b4.y, acc[1][1]);
            acc[1][2] = fmaf(a1, b4.z, acc[1][2]);
            acc[1][3] = fmaf(a1, b4.w, acc[1][3]);
            acc[2][0] = fmaf(a2, b4.x, acc[2][0]);
            acc[2][1] = fmaf(a2, b4.y, acc[2][1]);
            acc[2][2] = fmaf(a2, b4.z, acc[2][2]);
            acc[2][3] = fmaf(a2, b4.w, acc[2][3]);
            acc[3][0] = fmaf(a3, b4.x, acc[3][0]);
            acc[3][1] = fmaf(a3, b4.y, acc[3][1]);
            acc[3][2] = fmaf(a3, b4.z, acc[3][2]);
            acc[3][3] = fmaf(a3, b4.w, acc[3][3]);
        }
        __syncthreads();
    }

#pragma unroll
    for (int m = 0; m < 4; ++m) {
        const int c = c0 + cc * 4 + m;
        float4 v;
        if constexpr (SIG) {
            const float bb = bias[c];
            v.x = __fdividef(1.f, 1.f + __expf(-(acc[m][0] + bb)));
            v.y = __fdividef(1.f, 1.f + __expf(-(acc[m][1] + bb)));
            v.z = __fdividef(1.f, 1.f + __expf(-(acc[m][2] + bb)));
            v.w = __fdividef(1.f, 1.f + __expf(-(acc[m][3] + bb)));
        } else {
            v.x = acc[m][0];
            v.y = acc[m][1];
            v.z = acc[m][2];
            v.w = acc[m][3];
        }
        *(float4*)(Out + ((size_t)iq * 256 + c) * 1024 + t0 + tt * 4) = v;
    }
}

// float4 component by compile-time index
#define UC(arr, s) (((s) & 3) == 0 ? (arr)[(s) >> 2].x : \
                    ((s) & 3) == 1 ? (arr)[(s) >> 2].y : \
                    ((s) & 3) == 2 ? (arr)[(s) >> 2].z : (arr)[(s) >> 2].w)

// ---------------------------------------------------------------------------
// Block-Picard scan: 512 threads (8 waves, 2/SIMD). Blocks of BLK=16 steps.
//   Y[s][c] = sum_j T[s][j] * W[c][j]  via mfma_f32_16x16x32_f16:
//     A rows = 16 time steps of tanh-iterate (tx_block LDS, XOR-swizzled),
//     B = W^T fragments in VGPRs (wave owns 32 channels = 2 j-tiles),
//     C row = step (4g+reg), col = channel-within-tile (q).
//   Per iteration: 16 MFMA/wave + per-wave-private y exchange (no barrier)
//   + in-register 16-step sweep + tanh rewrite of tx rows; ONE barrier/iter.
//   MFMA per step: 32 (vs 128 in the per-step design) -> ~4x less pipe time.
//   Predictor for next block = converged rows (shift predictor, free); row 0
//   overwritten with exact tanh(x_block_start) at commit.
// ---------------------------------------------------------------------------
__global__ void __launch_bounds__(512, 1) scan_picard(const float* __restrict__ W,
                                                      const float* __restrict__ Up,
                                                      const float* __restrict__ dtp,
                                                      float* __restrict__ Xout) {
    // tx layout: byte = s*512 + (((j>>3) ^ s) & 31)*16 + (j&7)*2   (slot^row swizzle)
    __shared__ __align__(16) _Float16 tx0[BLK * C_CH];
    __shared__ __align__(16) _Float16 tx1[BLK * C_CH];
    __shared__ __align__(16) _Float16 ybuf[C_CH * BLK];  // [c][s] linear, per-wave private

    const int tid  = threadIdx.x;
    const int lane = tid & 63;
    const int wv   = tid >> 6;        // 0..7
    const int g    = lane >> 4;       // 0..3
    const int q    = lane & 15;       // 0..15
    const int cb   = wv << 5;         // wave channel base (32 channels)
    const int cown = cb + ((g & 1) << 4) + q;  // swept channel (2 lane-copies)
    const bool wr  = (g < 2);         // unique owner lanes (per channel)
    const int ghi  = g >> 1;          // row-half for tanh writes
    const float dt = *dtp;

    // B fragments: W rows for the wave's 2 j-tiles, fp16 (64 VGPRs).
    auto ld8 = [](const float* p) -> h8v {
        float4 a = *(const float4*)p;
        float4 b = *(const float4*)(p + 4);
        h8v r;
        r[0] = (_Float16)a.x; r[1] = (_Float16)a.y;
        r[2] = (_Float16)a.z; r[3] = (_Float16)a.w;
        r[4] = (_Float16)b.x; r[5] = (_Float16)b.y;
        r[6] = (_Float16)b.z; r[7] = (_Float16)b.w;
        return r;
    };
    h8v wB0[8], wB1[8];
    {
        const float* r0 = W + (size_t)(cb +  0 + q) * 256 + g * 8;
        const float* r1 = W + (size_t)(cb + 16 + q) * 256 + g * 8;
#pragma unroll
        for (int kt = 0; kt < 8; ++kt) {
            wB0[kt] = ld8(r0 + kt * 32);
            wB1[kt] = ld8(r1 + kt * 32);
        }
    }

    {   // zero both tx buffers (t=tanh(0)=0 everywhere; swizzle-invariant)
        h8v z = {};
        *(h8v*)&tx0[tid * 8] = z;
        *(h8v*)&tx1[tid * 8] = z;
    }
    __syncthreads();

    float  xprev = 0.f;
    float  xh[16];
    float4 uA[4], uB[4];
    {   // u for block 0
        const float* p = Up + (size_t)cown * 1024;
        uA[0] = *(const float4*)p;        uA[1] = *(const float4*)(p + 4);
        uA[2] = *(const float4*)(p + 8);  uA[3] = *(const float4*)(p + 12);
    }

    // ---- one Picard iteration ----
    auto iter = [&](const _Float16* txr, _Float16* txw, const float4 (&u)[4]) {
        // A fragments: lane (g,q) = row q, k-slice kt*32+8g..+7 (swizzled slot)
        h8v A[8];
#pragma unroll
        for (int kt = 0; kt < 8; ++kt) {
            const int slot = (4 * kt + g) ^ q;
            A[kt] = *(const h8v*)((const char*)txr + q * 512 + slot * 16);
        }
        f4v c0e = {0.f, 0.f, 0.f, 0.f};
        f4v c0o = c0e, c1e = c0e, c1o = c0e;
        c0e = __builtin_amdgcn_mfma_f32_16x16x32_f16(A[0], wB0[0], c0e, 0, 0, 0);
        c1e = __builtin_amdgcn_mfma_f32_16x16x32_f16(A[0], wB1[0], c1e, 0, 0, 0);
        c0o = __builtin_amdgcn_mfma_f32_16x16x32_f16(A[1], wB0[1], c0o, 0, 0, 0);
        c1o = __builtin_amdgcn_mfma_f32_16x16x32_f16(A[1], wB1[1], c1o, 0, 0, 0);
        c0e = __builtin_amdgcn_mfma_f32_16x16x32_f16(A[2], wB0[2], c0e, 0, 0, 0);
        c1e = __builtin_amdgcn_mfma_f32_16x16x32_f16(A[2], wB1[2], c1e, 0, 0, 0);
        c0o = __builtin_amdgcn_mfma_f32_16x16x32_f16(A[3], wB0[3], c0o, 0, 0, 0);
        c1o = __builtin_amdgcn_mfma_f32_16x16x32_f16(A[3], wB1[3], c1o, 0, 0, 0);
        c0e = __builtin_amdgcn_mfma_f32_16x16x32_f16(A[4], wB0[4], c0e, 0, 0, 0);
        c1e = __builtin_amdgcn_mfma_f32_16x16x32_f16(A[4], wB1[4], c1e, 0, 0, 0);
        c0o = __builtin_amdgcn_mfma_f32_16x16x32_f16(A[5], wB0[5], c0o, 0, 0, 0);
        c1o = __builtin_amdgcn_mfma_f32_16x16x32_f16(A[5], wB1[5], c1o, 0, 0, 0);
        c0e = __builtin_amdgcn_mfma_f32_16x16x32_f16(A[6], wB0[6], c0e, 0, 0, 0);
        c1e = __builtin_amdgcn_mfma_f32_16x16x32_f16(A[6], wB1[6], c1e, 0, 0, 0);
        c0o = __builtin_amdgcn_mfma_f32_16x16x32_f16(A[7], wB0[7], c0o, 0, 0, 0);
        c1o = __builtin_amdgcn_mfma_f32_16x16x32_f16(A[7], wB1[7], c1o, 0, 0, 0);
        const f4v C0 = c0e + c0o;   // y[steps 4g..4g+3][channel cb+q]
        const f4v C1 = c1e + c1o;   // y[steps 4g..4g+3][channel cb+16+q]

        // publish y to the wave-private exchange buffer ([c][s], b64 per tile)
        h4v p0, p1;
#pragma unroll
        for (int i = 0; i < 4; ++i) {
            p0[i] = (_Float16)C0[i];
            p1[i] = (_Float16)C1[i];
        }
        *(h4v*)&ybuf[(cb + q) * 16 + 4 * g]      = p0;
        *(h4v*)&ybuf[(cb + 16 + q) * 16 + 4 * g] = p1;
        asm volatile("s_waitcnt lgkmcnt(0)" ::: "memory");  // intra-wave only
        __builtin_amdgcn_sched_barrier(0);
        const h8v y0 = *(const h8v*)&ybuf[cown * 16];
        const h8v y1 = *(const h8v*)&ybuf[cown * 16 + 8];

        // sequential 16-step sweep (exact x-chain, y from current iterate)
        float xx = xprev;
#pragma unroll
        for (int s = 0; s < 16; ++s) {
            const float yv = (s < 8) ? (float)y0[s] : (float)y1[s - 8];
            xx = fmaf(dt, yv + UC(u, s) - xx, xx);
            xh[s] = xx;
        }

        // tanh rewrite: rows 1..8 (ghi=0) / 9..15 (ghi=1) of this channel
#pragma unroll
        for (int k = 0; k < 8; ++k) {
            const int   r  = ghi * 8 + 1 + k;                  // runtime row
            const float xv = ghi ? xh[8 + k] : xh[k];          // static idx
            const float av = fabsf(xv);
            const float e  = __expf(-2.f * av);
            const float th = (1.f - e) * __fdividef(1.f, 1.f + e);
            if (r < 16) {
                char* wp = (char*)txw + r * 512 + (((cown >> 3) ^ r) & 31) * 16 + (cown & 7) * 2;
                *(_Float16*)wp = (_Float16)copysignf(th, xv);
            }
        }
        asm volatile("s_waitcnt lgkmcnt(0)" ::: "memory");
        __builtin_amdgcn_s_barrier();
        __builtin_amdgcn_sched_barrier(0);
    };

    // ---- one 16-step block: prefetch next u, MITER iterations, commit ----
    auto block = [&](const float4 (&ucur)[4], float4 (&unext)[4], int s0) {
        {   // prefetch u for the next block (last-block overrun lands in out1)
            const int sN = s0 + BLK;
            const float* p = Up + (((size_t)(sN >> 10) << 8) + cown) * 1024 + (sN & 1023);
            unext[0] = *(const float4*)p;        unext[1] = *(const float4*)(p + 4);
            unext[2] = *(const float4*)(p + 8);  unext[3] = *(const float4*)(p + 12);
        }
        iter(tx0, tx1, ucur);   // MITER = 4, statically unrolled parity
        iter(tx1, tx0, ucur);
        iter(tx0, tx1, ucur);
        iter(tx1, tx0, ucur);   // ends with tx0 = converged rows (predictor)

        xprev = xh[15];
        if (wr) {
            float* xp = Xout + (((size_t)(s0 >> 10) << 8) + cown) * 1024 + (s0 & 1023);
            *(float4*)(xp + 0)  = make_float4(xh[0],  xh[1],  xh[2],  xh[3]);
            *(float4*)(xp + 4)  = make_float4(xh[4],  xh[5],  xh[6],  xh[7]);
            *(float4*)(xp + 8)  = make_float4(xh[8],  xh[9],  xh[10], xh[11]);
            *(float4*)(xp + 12) = make_float4(xh[12], xh[13], xh[14], xh[15]);
            // row 0 (exact tanh of block-start state) into BOTH buffers
            const float av = fabsf(xprev);
            const float e  = __expf(-2.f * av);
            const _Float16 t16 =
                (_Float16)copysignf((1.f - e) * __fdividef(1.f, 1.f + e), xprev);
            tx0[cown] = t16;   // row 0: swizzle(0, slot) = slot -> linear
            tx1[cown] = t16;
        }
        asm volatile("s_waitcnt lgkmcnt(0)" ::: "memory");
        __builtin_amdgcn_s_barrier();
        __builtin_amdgcn_sched_barrier(0);
    };

#pragma unroll 1
    for (int it = 0; it < NSTEP / (2 * BLK); ++it) {
        block(uA, uB, it * 32);
        block(uB, uA, it * 32 + 16);
    }
}

// ---------------------------------------------------------------------------
extern "C" void kernel_launch(void* const* d_in, const int* in_sizes, int n_in,
                              void* d_out, int out_size, void* d_ws, size_t ws_size,
                              hipStream_t stream) {
    const float* u  = (const float*)d_in[0];
    const float* dt = (const float*)d_in[1];
    const float* W  = (const float*)d_in[2];
    const float* M  = (const float*)d_in[3];
    const float* H  = (const float*)d_in[4];
    const float* b  = (const float*)d_in[5];

    float* out0 = (float*)d_out;                        // outputs region (Y)
    float* out1 = out0 + (size_t)IQ * C_CH * T_SEQ;     // membrane region (X)

    dim3 ggrid(T_SEQ / 64, C_CH / 64, IQ);

    // 1) Uproj[iq][c][t] = M @ u_iq  -> staged in out0 (overwritten by Y later)
    gemm_ct<false><<<ggrid, 256, 0, stream>>>(M, u, nullptr, out0);

    // 2) Block-Picard scan over 65536 steps; membrane potentials -> out1
    scan_picard<<<1, 512, 0, stream>>>(W, out0, dt, out1);

    // 3) Y[iq][c][t] = sigmoid(H @ X_iq + b) -> out0
    gemm_ct<true><<<ggrid, 256, 0, stream>>>(H, out1, b, out0);
}

// Round 7
// 17710.370 us; speedup vs baseline: 12.0394x; 1.3162x over previous
//
#include <hip/hip_runtime.h>
#include <math.h>

#define IQ     64
#define C_CH   256
#define T_SEQ  1024
#define NSTEP  (IQ * T_SEQ)
#define BLK    16   // steps per Picard block (= MFMA rows)

typedef _Float16 h8v __attribute__((ext_vector_type(8)));
typedef _Float16 h4v __attribute__((ext_vector_type(4)));
typedef float    f4v __attribute__((ext_vector_type(4)));

// ---------------------------------------------------------------------------
// GEMM in [iq][c][t] layout (unchanged):
//   Out[iq][c][t] = act( sum_j A[c][j] * In[iq][j][t] (+ bias[c]) )
// ---------------------------------------------------------------------------
template <bool SIG>
__global__ void __launch_bounds__(256) gemm_ct(const float* __restrict__ A,
                                               const float* __restrict__ In,
                                               const float* __restrict__ bias,
                                               float* __restrict__ Out) {
    __shared__ float aT[64][65];
    __shared__ float bI[64][68];

    const int tid = threadIdx.x;
    const int t0  = blockIdx.x * 64;
    const int c0  = blockIdx.y * 64;
    const int iq  = blockIdx.z;

    const int tt = tid & 15;
    const int cc = tid >> 4;
    const int lr = tid >> 2;
    const int lq = tid & 3;

    float acc[4][4];
#pragma unroll
    for (int m = 0; m < 4; ++m)
#pragma unroll
        for (int n = 0; n < 4; ++n) acc[m][n] = 0.f;

    for (int kc = 0; kc < 4; ++kc) {
        const float* Ar = A + (size_t)(c0 + lr) * 256 + kc * 64;
#pragma unroll
        for (int k2 = 0; k2 < 4; ++k2) {
            float4 v = *(const float4*)(Ar + lq * 4 + k2 * 16);
            int jj = lq * 4 + k2 * 16;
            aT[jj + 0][lr] = v.x;
            aT[jj + 1][lr] = v.y;
            aT[jj + 2][lr] = v.z;
            aT[jj + 3][lr] = v.w;
        }
        const float* Ir = In + ((size_t)iq * 256 + kc * 64 + lr) * 1024 + t0;
#pragma unroll
        for (int k2 = 0; k2 < 4; ++k2) {
            float4 v = *(const float4*)(Ir + lq * 4 + k2 * 16);
            *(float4*)&bI[lr][lq * 4 + k2 * 16] = v;
        }
        __syncthreads();

#pragma unroll 8
        for (int jj = 0; jj < 64; ++jj) {
            const float a0 = aT[jj][cc * 4 + 0];
            const float a1 = aT[jj][cc * 4 + 1];
            const float a2 = aT[jj][cc * 4 + 2];
            const float a3 = aT[jj][cc * 4 + 3];
            const float4 b4 = *(const float4*)&bI[jj][tt * 4];
            acc[0][0] = fmaf(a0, b4.x, acc[0][0]);
            acc[0][1] = fmaf(a0, b4.y, acc[0][1]);
            acc[0][2] = fmaf(a0, b4.z, acc[0][2]);
            acc[0][3] = fmaf(a0, b4.w, acc[0][3]);
            acc[1][0] = fmaf(a1, b4.x, acc[1][0]);
            acc[1][1] = fmaf(a1, b4.y, acc[1][1]);
            acc[1][2] = fmaf(a1, b4.z, acc[1][2]);
            acc[1][3] = fmaf(a1, b4.w, acc[1][3]);
            acc[2][0] = fmaf(a2, b4.x, acc[2][0]);
            acc[2][1] = fmaf(a2, b4.y, acc[2][1]);
            acc[2][2] = fmaf(a2, b4.z, acc[2][2]);
            acc[2][3] = fmaf(a2, b4.w, acc[2][3]);
            acc[3][0] = fmaf(a3, b4.x, acc[3][0]);
            acc[3][1] = fmaf(a3, b4.y, acc[3][1]);
            acc[3][2] = fmaf(a3, b4.z, acc[3][2]);
            acc[3][3] = fmaf(a3, b4.w, acc[3][3]);
        }
        __syncthreads();
    }

#pragma unroll
    for (int m = 0; m < 4; ++m) {
        const int c = c0 + cc * 4 + m;
        float4 v;
        if constexpr (SIG) {
            const float bb = bias[c];
            v.x = __fdividef(1.f, 1.f + __expf(-(acc[m][0] + bb)));
            v.y = __fdividef(1.f, 1.f + __expf(-(acc[m][1] + bb)));
            v.z = __fdividef(1.f, 1.f + __expf(-(acc[m][2] + bb)));
            v.w = __fdividef(1.f, 1.f + __expf(-(acc[m][3] + bb)));
        } else {
            v.x = acc[m][0];
            v.y = acc[m][1];
            v.z = acc[m][2];
            v.w = acc[m][3];
        }
        *(float4*)(Out + ((size_t)iq * 256 + c) * 1024 + t0 + tt * 4) = v;
    }
}

// float4 component by compile-time index
#define UC(arr, s) (((s) & 3) == 0 ? (arr)[(s) >> 2].x : \
                    ((s) & 3) == 1 ? (arr)[(s) >> 2].y : \
                    ((s) & 3) == 2 ? (arr)[(s) >> 2].z : (arr)[(s) >> 2].w)

// ---------------------------------------------------------------------------
// Block-Picard scan, round-7 tuning of the round-6 structure:
//   - MITER = 3 (factorial Picard contraction: e3 ~ e0*0.32^3/6; added x-error
//     ~1.6e-3/block, damped steady-state ~3e-3 -- under the fp16 floor regime).
//     3 is odd -> blocks alternate tx-buffer parity.
//   - ybuf stride 24 h16 (48 B, 16B-aligned): uniform bank coverage on both
//     the h4v writes and b128 reads (round 6: stride 16 -> 4M conflicts).
//   - All per-lane LDS byte offsets (A fragments, tanh scatter) are static:
//     precomputed once, buffers addressed as base + offset.
//   - Only ONE scheduling fence per iteration (after the barrier), so the
//     compiler can interleave A-loads, MFMAs, and VALU tail freely.
// ---------------------------------------------------------------------------
__global__ void __launch_bounds__(512, 1) scan_picard(const float* __restrict__ W,
                                                      const float* __restrict__ Up,
                                                      const float* __restrict__ dtp,
                                                      float* __restrict__ Xout) {
    // tx layout: byte = s*512 + (((c>>3) ^ s) & 31)*16 + (c&7)*2  (slot^row swizzle)
    __shared__ __align__(16) _Float16 tx0[BLK * C_CH];
    __shared__ __align__(16) _Float16 tx1[BLK * C_CH];
    __shared__ __align__(16) _Float16 ybuf[C_CH * 24];  // [c][s(16)+pad(8)]

    const int tid  = threadIdx.x;
    const int lane = tid & 63;
    const int wv   = tid >> 6;        // 0..7
    const int g    = lane >> 4;       // 0..3
    const int q    = lane & 15;       // 0..15
    const int cb   = wv << 5;         // wave channel base (32 channels)
    const int cown = cb + ((g & 1) << 4) + q;  // swept channel (2 lane-copies)
    const bool wr  = (g < 2);         // unique owner lanes (per channel)
    const int ghi  = g >> 1;          // row-half for tanh writes
    const float dt = *dtp;

    // B fragments: W rows for the wave's 2 j-tiles, fp16 (64 VGPRs).
    auto ld8 = [](const float* p) -> h8v {
        float4 a = *(const float4*)p;
        float4 b = *(const float4*)(p + 4);
        h8v r;
        r[0] = (_Float16)a.x; r[1] = (_Float16)a.y;
        r[2] = (_Float16)a.z; r[3] = (_Float16)a.w;
        r[4] = (_Float16)b.x; r[5] = (_Float16)b.y;
        r[6] = (_Float16)b.z; r[7] = (_Float16)b.w;
        return r;
    };
    h8v wB0[8], wB1[8];
    {
        const float* r0 = W + (size_t)(cb +  0 + q) * 256 + g * 8;
        const float* r1 = W + (size_t)(cb + 16 + q) * 256 + g * 8;
#pragma unroll
        for (int kt = 0; kt < 8; ++kt) {
            wB0[kt] = ld8(r0 + kt * 32);
            wB1[kt] = ld8(r1 + kt * 32);
        }
    }

    // Static per-lane LDS byte offsets (buffer-relative).
    int aoff[8];   // A-fragment reads: row q, k-slice kt*32+8g, swizzled slot
#pragma unroll
    for (int kt = 0; kt < 8; ++kt) aoff[kt] = q * 512 + (((4 * kt + g) ^ q) * 16);
    int toff[8];   // tanh scatter writes: row r = ghi*8+1+k of channel cown
#pragma unroll
    for (int k = 0; k < 8; ++k) {
        const int r = ghi * 8 + 1 + k;  // ghi=1,k=7 -> r=16: guarded, never stored
        toff[k] = r * 512 + ((((cown >> 3) ^ r) & 31) * 16) + (cown & 7) * 2;
    }

    {   // zero both tx buffers (tanh(0)=0; swizzle-invariant)
        h8v z = {};
        *(h8v*)&tx0[tid * 8] = z;
        *(h8v*)&tx1[tid * 8] = z;
    }
    __syncthreads();

    float  xprev = 0.f;
    float  xh[16];
    float4 uA[4], uB[4];
    {   // u for block 0
        const float* p = Up + (size_t)cown * 1024;
        uA[0] = *(const float4*)p;        uA[1] = *(const float4*)(p + 4);
        uA[2] = *(const float4*)(p + 8);  uA[3] = *(const float4*)(p + 12);
    }

    // ---- one Picard iteration (reads txr rows, rewrites txw rows 1..15) ----
    auto iter = [&](const _Float16* txr, _Float16* txw, const float4 (&u)[4]) {
        h8v A[8];
#pragma unroll
        for (int kt = 0; kt < 8; ++kt)
            A[kt] = *(const h8v*)((const char*)txr + aoff[kt]);
        f4v c0e = {0.f, 0.f, 0.f, 0.f};
        f4v c0o = c0e, c1e = c0e, c1o = c0e;
        c0e = __builtin_amdgcn_mfma_f32_16x16x32_f16(A[0], wB0[0], c0e, 0, 0, 0);
        c1e = __builtin_amdgcn_mfma_f32_16x16x32_f16(A[0], wB1[0], c1e, 0, 0, 0);
        c0o = __builtin_amdgcn_mfma_f32_16x16x32_f16(A[1], wB0[1], c0o, 0, 0, 0);
        c1o = __builtin_amdgcn_mfma_f32_16x16x32_f16(A[1], wB1[1], c1o, 0, 0, 0);
        c0e = __builtin_amdgcn_mfma_f32_16x16x32_f16(A[2], wB0[2], c0e, 0, 0, 0);
        c1e = __builtin_amdgcn_mfma_f32_16x16x32_f16(A[2], wB1[2], c1e, 0, 0, 0);
        c0o = __builtin_amdgcn_mfma_f32_16x16x32_f16(A[3], wB0[3], c0o, 0, 0, 0);
        c1o = __builtin_amdgcn_mfma_f32_16x16x32_f16(A[3], wB1[3], c1o, 0, 0, 0);
        c0e = __builtin_amdgcn_mfma_f32_16x16x32_f16(A[4], wB0[4], c0e, 0, 0, 0);
        c1e = __builtin_amdgcn_mfma_f32_16x16x32_f16(A[4], wB1[4], c1e, 0, 0, 0);
        c0o = __builtin_amdgcn_mfma_f32_16x16x32_f16(A[5], wB0[5], c0o, 0, 0, 0);
        c1o = __builtin_amdgcn_mfma_f32_16x16x32_f16(A[5], wB1[5], c1o, 0, 0, 0);
        c0e = __builtin_amdgcn_mfma_f32_16x16x32_f16(A[6], wB0[6], c0e, 0, 0, 0);
        c1e = __builtin_amdgcn_mfma_f32_16x16x32_f16(A[6], wB1[6], c1e, 0, 0, 0);
        c0o = __builtin_amdgcn_mfma_f32_16x16x32_f16(A[7], wB0[7], c0o, 0, 0, 0);
        c1o = __builtin_amdgcn_mfma_f32_16x16x32_f16(A[7], wB1[7], c1o, 0, 0, 0);
        const f4v C0 = c0e + c0o;   // y[steps 4g..4g+3][channel cb+q]
        const f4v C1 = c1e + c1o;   // y[steps 4g..4g+3][channel cb+16+q]

        // y exchange (wave-private region of ybuf; stride 24 -> conflict-free)
        h4v p0, p1;
#pragma unroll
        for (int i = 0; i < 4; ++i) {
            p0[i] = (_Float16)C0[i];
            p1[i] = (_Float16)C1[i];
        }
        *(h4v*)&ybuf[(cb + q) * 24 + 4 * g]      = p0;
        *(h4v*)&ybuf[(cb + 16 + q) * 24 + 4 * g] = p1;
        asm volatile("s_waitcnt lgkmcnt(0)" ::: "memory");  // intra-wave W->R
        const h8v y0 = *(const h8v*)&ybuf[cown * 24];
        const h8v y1 = *(const h8v*)&ybuf[cown * 24 + 8];

        // sequential 16-step sweep (exact x-chain, y from current iterate)
        float xx = xprev;
#pragma unroll
        for (int s = 0; s < 16; ++s) {
            const float yv = (s < 8) ? (float)y0[s] : (float)y1[s - 8];
            xx = fmaf(dt, yv + UC(u, s) - xx, xx);
            xh[s] = xx;
        }

        // tanh rewrite: rows 1..8 (ghi=0) / 9..15 (ghi=1, 7 rows) of channel
#pragma unroll
        for (int k = 0; k < 8; ++k) {
            const float xv = ghi ? xh[8 + k] : xh[k];
            const float av = fabsf(xv);
            const float e  = __expf(-2.f * av);
            const float th = (1.f - e) * __fdividef(1.f, 1.f + e);
            if (k < 7 || !ghi)
                *(_Float16*)((char*)txw + toff[k]) = (_Float16)copysignf(th, xv);
        }
        asm volatile("s_waitcnt lgkmcnt(0)" ::: "memory");  // writes visible
        __builtin_amdgcn_s_barrier();
        __builtin_amdgcn_sched_barrier(0);  // next iter's A-reads stay below
    };

    // ---- commit: write x history, refresh row 0 (exact) in BOTH buffers ----
    auto commit = [&](int s0) {
        xprev = xh[15];
        if (wr) {
            float* xp = Xout + (((size_t)(s0 >> 10) << 8) + cown) * 1024 + (s0 & 1023);
            *(float4*)(xp + 0)  = make_float4(xh[0],  xh[1],  xh[2],  xh[3]);
            *(float4*)(xp + 4)  = make_float4(xh[4],  xh[5],  xh[6],  xh[7]);
            *(float4*)(xp + 8)  = make_float4(xh[8],  xh[9],  xh[10], xh[11]);
            *(float4*)(xp + 12) = make_float4(xh[12], xh[13], xh[14], xh[15]);
            const float av = fabsf(xprev);
            const float e  = __expf(-2.f * av);
            const _Float16 t16 =
                (_Float16)copysignf((1.f - e) * __fdividef(1.f, 1.f + e), xprev);
            tx0[cown] = t16;   // row 0 swizzle is identity
            tx1[cown] = t16;
        }
        asm volatile("s_waitcnt lgkmcnt(0)" ::: "memory");
        __builtin_amdgcn_s_barrier();
        __builtin_amdgcn_sched_barrier(0);
    };

    // Two blocks per loop; MITER=3 flips predictor parity each block.
#pragma unroll 1
    for (int it = 0; it < NSTEP / (2 * BLK); ++it) {
        const int s0 = it * 2 * BLK;

        {   // prefetch u for odd block
            const int sN = s0 + BLK;
            const float* p = Up + (((size_t)(sN >> 10) << 8) + cown) * 1024 + (sN & 1023);
            uB[0] = *(const float4*)p;        uB[1] = *(const float4*)(p + 4);
            uB[2] = *(const float4*)(p + 8);  uB[3] = *(const float4*)(p + 12);
        }
        // even block: predictor in tx0 -> ends in tx1
        iter(tx0, tx1, uA);
        iter(tx1, tx0, uA);
        iter(tx0, tx1, uA);
        commit(s0);

        {   // prefetch u for next even block (last overrun lands in out1: unused)
            const int sN = s0 + 2 * BLK;
            const float* p = Up + (((size_t)(sN >> 10) << 8) + cown) * 1024 + (sN & 1023);
            uA[0] = *(const float4*)p;        uA[1] = *(const float4*)(p + 4);
            uA[2] = *(const float4*)(p + 8);  uA[3] = *(const float4*)(p + 12);
        }
        // odd block: predictor in tx1 -> ends in tx0
        iter(tx1, tx0, uB);
        iter(tx0, tx1, uB);
        iter(tx1, tx0, uB);
        commit(s0 + BLK);
    }
}

// ---------------------------------------------------------------------------
extern "C" void kernel_launch(void* const* d_in, const int* in_sizes, int n_in,
                              void* d_out, int out_size, void* d_ws, size_t ws_size,
                              hipStream_t stream) {
    const float* u  = (const float*)d_in[0];
    const float* dt = (const float*)d_in[1];
    const float* W  = (const float*)d_in[2];
    const float* M  = (const float*)d_in[3];
    const float* H  = (const float*)d_in[4];
    const float* b  = (const float*)d_in[5];

    float* out0 = (float*)d_out;                        // outputs region (Y)
    float* out1 = out0 + (size_t)IQ * C_CH * T_SEQ;     // membrane region (X)

    dim3 ggrid(T_SEQ / 64, C_CH / 64, IQ);

    // 1) Uproj[iq][c][t] = M @ u_iq  -> staged in out0 (overwritten by Y later)
    gemm_ct<false><<<ggrid, 256, 0, stream>>>(M, u, nullptr, out0);

    // 2) Block-Picard scan over 65536 steps; membrane potentials -> out1
    scan_picard<<<1, 512, 0, stream>>>(W, out0, dt, out1);

    // 3) Y[iq][c][t] = sigmoid(H @ X_iq + b) -> out0
    gemm_ct<true><<<ggrid, 256, 0, stream>>>(H, out1, b, out0);
}

// Round 9
// 14341.249 us; speedup vs baseline: 14.8678x; 1.2349x over previous
//
#include <hip/hip_runtime.h>
#include <math.h>

#define IQ     64
#define C_CH   256
#define T_SEQ  1024
#define NSTEP  (IQ * T_SEQ)
#define BLK    16   // steps per Picard block (= MFMA rows)

typedef _Float16 h8v __attribute__((ext_vector_type(8)));
typedef _Float16 h4v __attribute__((ext_vector_type(4)));
typedef float    f4v __attribute__((ext_vector_type(4)));

// ---------------------------------------------------------------------------
// GEMM in [iq][c][t] layout (unchanged):
//   Out[iq][c][t] = act( sum_j A[c][j] * In[iq][j][t] (+ bias[c]) )
// ---------------------------------------------------------------------------
template <bool SIG>
__global__ void __launch_bounds__(256) gemm_ct(const float* __restrict__ A,
                                               const float* __restrict__ In,
                                               const float* __restrict__ bias,
                                               float* __restrict__ Out) {
    __shared__ float aT[64][65];
    __shared__ float bI[64][68];

    const int tid = threadIdx.x;
    const int t0  = blockIdx.x * 64;
    const int c0  = blockIdx.y * 64;
    const int iq  = blockIdx.z;

    const int tt = tid & 15;
    const int cc = tid >> 4;
    const int lr = tid >> 2;
    const int lq = tid & 3;

    float acc[4][4];
#pragma unroll
    for (int m = 0; m < 4; ++m)
#pragma unroll
        for (int n = 0; n < 4; ++n) acc[m][n] = 0.f;

    for (int kc = 0; kc < 4; ++kc) {
        const float* Ar = A + (size_t)(c0 + lr) * 256 + kc * 64;
#pragma unroll
        for (int k2 = 0; k2 < 4; ++k2) {
            float4 v = *(const float4*)(Ar + lq * 4 + k2 * 16);
            int jj = lq * 4 + k2 * 16;
            aT[jj + 0][lr] = v.x;
            aT[jj + 1][lr] = v.y;
            aT[jj + 2][lr] = v.z;
            aT[jj + 3][lr] = v.w;
        }
        const float* Ir = In + ((size_t)iq * 256 + kc * 64 + lr) * 1024 + t0;
#pragma unroll
        for (int k2 = 0; k2 < 4; ++k2) {
            float4 v = *(const float4*)(Ir + lq * 4 + k2 * 16);
            *(float4*)&bI[lr][lq * 4 + k2 * 16] = v;
        }
        __syncthreads();

#pragma unroll 8
        for (int jj = 0; jj < 64; ++jj) {
            const float a0 = aT[jj][cc * 4 + 0];
            const float a1 = aT[jj][cc * 4 + 1];
            const float a2 = aT[jj][cc * 4 + 2];
            const float a3 = aT[jj][cc * 4 + 3];
            const float4 b4 = *(const float4*)&bI[jj][tt * 4];
            acc[0][0] = fmaf(a0, b4.x, acc[0][0]);
            acc[0][1] = fmaf(a0, b4.y, acc[0][1]);
            acc[0][2] = fmaf(a0, b4.z, acc[0][2]);
            acc[0][3] = fmaf(a0, b4.w, acc[0][3]);
            acc[1][0] = fmaf(a1, b4.x, acc[1][0]);
            acc[1][1] = fmaf(a1, b4.y, acc[1][1]);
            acc[1][2] = fmaf(a1, b4.z, acc[1][2]);
            acc[1][3] = fmaf(a1, b4.w, acc[1][3]);
            acc[2][0] = fmaf(a2, b4.x, acc[2][0]);
            acc[2][1] = fmaf(a2, b4.y, acc[2][1]);
            acc[2][2] = fmaf(a2, b4.z, acc[2][2]);
            acc[2][3] = fmaf(a2, b4.w, acc[2][3]);
            acc[3][0] = fmaf(a3, b4.x, acc[3][0]);
            acc[3][1] = fmaf(a3, b4.y, acc[3][1]);
            acc[3][2] = fmaf(a3, b4.z, acc[3][2]);
            acc[3][3] = fmaf(a3, b4.w, acc[3][3]);
        }
        __syncthreads();
    }

#pragma unroll
    for (int m = 0; m < 4; ++m) {
        const int c = c0 + cc * 4 + m;
        float4 v;
        if constexpr (SIG) {
            const float bb = bias[c];
            v.x = __fdividef(1.f, 1.f + __expf(-(acc[m][0] + bb)));
            v.y = __fdividef(1.f, 1.f + __expf(-(acc[m][1] + bb)));
            v.z = __fdividef(1.f, 1.f + __expf(-(acc[m][2] + bb)));
            v.w = __fdividef(1.f, 1.f + __expf(-(acc[m][3] + bb)));
        } else {
            v.x = acc[m][0];
            v.y = acc[m][1];
            v.z = acc[m][2];
            v.w = acc[m][3];
        }
        *(float4*)(Out + ((size_t)iq * 256 + c) * 1024 + t0 + tt * 4) = v;
    }
}

// ---------------------------------------------------------------------------
// Block-Picard scan, round 9 (= round-8 design, intrinsic name fixed):
//   Per iteration (per wave, 2 j-tiles = 32 channels):
//     Y = T @ W^T              (16 x mfma_f32_16x16x32_f16, B=W in VGPRs)
//     R = dt*Y + du            (8 fma, in C-layout; du = dt*u precomputed)
//     X = L @ R + a^{s+1}xprev (2 x mfma_f32_16x16x16f16; L = lower-tri
//                               Toeplitz a^{s-j}, static per-lane A-frag;
//                               C-in = aC[reg]*xprev, 8 mul)
//     tanh(X) -> tx rows s+1   (8 tanh + 8 ds_write_b16, swizzled)
//   No cross-lane y exchange (ybuf deleted): Y, R, X stay in the MFMA
//   C-layout (row = step 4g+reg, col = channel q). u and Xout are handled
//   in C-layout (per-lane float4, no write-mask, no redundancy).
//   One lgkmcnt+barrier per iteration. xprev broadcast via 256-f32 LDS at
//   commit (intra-wave, lgkmcnt only).
// ---------------------------------------------------------------------------
__global__ void __launch_bounds__(512, 1) scan_picard(const float* __restrict__ W,
                                                      const float* __restrict__ Up,
                                                      const float* __restrict__ dtp,
                                                      float* __restrict__ Xout) {
    // tx layout: byte = s*512 + (((c>>3) ^ s) & 31)*16 + (c&7)*2  (slot^row swizzle)
    __shared__ __align__(16) _Float16 tx0[BLK * C_CH];
    __shared__ __align__(16) _Float16 tx1[BLK * C_CH];
    __shared__ __align__(16) float    xpb[C_CH];   // xprev broadcast

    const int tid  = threadIdx.x;
    const int lane = tid & 63;
    const int wv   = tid >> 6;        // 0..7
    const int g    = lane >> 4;       // 0..3
    const int q    = lane & 15;       // 0..15
    const int cb   = wv << 5;         // wave channel base (32 channels)
    const int ch0  = cb + q;          // j-tile 0 channel
    const int ch1  = cb + 16 + q;     // j-tile 1 channel
    const float dt = *dtp;
    const float a  = 1.f - dt;

    // B fragments for the W-MFMA (fp16, validated layout).
    auto ld8 = [](const float* p) -> h8v {
        float4 x = *(const float4*)p;
        float4 y = *(const float4*)(p + 4);
        h8v r;
        r[0] = (_Float16)x.x; r[1] = (_Float16)x.y;
        r[2] = (_Float16)x.z; r[3] = (_Float16)x.w;
        r[4] = (_Float16)y.x; r[5] = (_Float16)y.y;
        r[6] = (_Float16)y.z; r[7] = (_Float16)y.w;
        return r;
    };
    h8v wB0[8], wB1[8];
    {
        const float* r0 = W + (size_t)ch0 * 256 + g * 8;
        const float* r1 = W + (size_t)ch1 * 256 + g * 8;
#pragma unroll
        for (int kt = 0; kt < 8; ++kt) {
            wB0[kt] = ld8(r0 + kt * 32);
            wB1[kt] = ld8(r1 + kt * 32);
        }
    }

    // Static per-lane constants for the L-MFMA.
    //   A-frag: A[i=q][k=4g+f] = L[q][4g+f] = (q>=4g+f) ? a^(q-4g-f) : 0
    //   C-in coefficients: aC[reg] = a^(4g+reg+1)
    h4v Lf;
    float aC[4];
    {
        const float l2a = log2f(a);
#pragma unroll
        for (int f = 0; f < 4; ++f) {
            const int e = q - (4 * g + f);
            Lf[f] = (e >= 0) ? (_Float16)exp2f((float)e * l2a) : (_Float16)0.f;
        }
        const float a2 = a * a, a4 = a2 * a2;
        const float ag = (g == 0) ? 1.f : (g == 1) ? a4 : (g == 2) ? a4 * a4 : a4 * a4 * a4;
        aC[0] = ag * a;
        aC[1] = ag * a2;
        aC[2] = ag * a2 * a;
        aC[3] = ag * a4;
    }

    // Static per-lane LDS byte offsets.
    int aoff[8];   // A-frag reads (W-MFMA): row q, k-slice kt*32+8g, swizzled
#pragma unroll
    for (int kt = 0; kt < 8; ++kt) aoff[kt] = q * 512 + (((4 * kt + g) ^ q) * 16);
    int toff0[4], toff1[4];  // tanh scatter: row r = 4g+i+1 of ch0 / ch1
#pragma unroll
    for (int i = 0; i < 4; ++i) {
        const int r = 4 * g + i + 1;   // r==16 (g==3,i==3) is guarded at use
        toff0[i] = r * 512 + ((((ch0 >> 3) ^ r) & 31) * 16) + (ch0 & 7) * 2;
        toff1[i] = r * 512 + ((((ch1 >> 3) ^ r) & 31) * 16) + (ch1 & 7) * 2;
    }

    {   // zero tx buffers (tanh(0)=0) and xprev broadcast buffer
        h8v z = {};
        *(h8v*)&tx0[tid * 8] = z;
        *(h8v*)&tx1[tid * 8] = z;
        if (tid < 256) xpb[tid] = 0.f;
    }
    __syncthreads();

    auto tanh16 = [](float xv) -> _Float16 {
        const float av = fabsf(xv);
        const float e  = __expf(-2.f * av);
        const float th = (1.f - e) * __fdividef(1.f, 1.f + e);
        return (_Float16)copysignf(th, xv);
    };

    float xq0 = 0.f, xq1 = 0.f;   // xprev of ch0/ch1 (same across g-copies)
    f4v   Xc0, Xc1;               // last iteration's X (C-layout)
    float du0[4], du1[4];         // dt*u for this block, C-layout
    float4 un0, un1;              // u prefetch

    auto loadu = [&](int s, float4& o0, float4& o1) {
        const size_t base = ((size_t)(s >> 10) << 8);
        o0 = *(const float4*)(Up + (base + ch0) * 1024 + (s & 1023) + 4 * g);
        o1 = *(const float4*)(Up + (base + ch1) * 1024 + (s & 1023) + 4 * g);
    };

    loadu(0, un0, un1);
    du0[0] = dt * un0.x; du0[1] = dt * un0.y; du0[2] = dt * un0.z; du0[3] = dt * un0.w;
    du1[0] = dt * un1.x; du1[1] = dt * un1.y; du1[2] = dt * un1.z; du1[3] = dt * un1.w;

    // ---- one Picard iteration ----
    auto iter = [&](const _Float16* txr, _Float16* txw) {
        h8v A[8];
#pragma unroll
        for (int kt = 0; kt < 8; ++kt)
            A[kt] = *(const h8v*)((const char*)txr + aoff[kt]);
        f4v c0e = {0.f, 0.f, 0.f, 0.f};
        f4v c0o = c0e, c1e = c0e, c1o = c0e;
        c0e = __builtin_amdgcn_mfma_f32_16x16x32_f16(A[0], wB0[0], c0e, 0, 0, 0);
        c1e = __builtin_amdgcn_mfma_f32_16x16x32_f16(A[0], wB1[0], c1e, 0, 0, 0);
        c0o = __builtin_amdgcn_mfma_f32_16x16x32_f16(A[1], wB0[1], c0o, 0, 0, 0);
        c1o = __builtin_amdgcn_mfma_f32_16x16x32_f16(A[1], wB1[1], c1o, 0, 0, 0);
        c0e = __builtin_amdgcn_mfma_f32_16x16x32_f16(A[2], wB0[2], c0e, 0, 0, 0);
        c1e = __builtin_amdgcn_mfma_f32_16x16x32_f16(A[2], wB1[2], c1e, 0, 0, 0);
        c0o = __builtin_amdgcn_mfma_f32_16x16x32_f16(A[3], wB0[3], c0o, 0, 0, 0);
        c1o = __builtin_amdgcn_mfma_f32_16x16x32_f16(A[3], wB1[3], c1o, 0, 0, 0);
        c0e = __builtin_amdgcn_mfma_f32_16x16x32_f16(A[4], wB0[4], c0e, 0, 0, 0);
        c1e = __builtin_amdgcn_mfma_f32_16x16x32_f16(A[4], wB1[4], c1e, 0, 0, 0);
        c0o = __builtin_amdgcn_mfma_f32_16x16x32_f16(A[5], wB0[5], c0o, 0, 0, 0);
        c1o = __builtin_amdgcn_mfma_f32_16x16x32_f16(A[5], wB1[5], c1o, 0, 0, 0);
        c0e = __builtin_amdgcn_mfma_f32_16x16x32_f16(A[6], wB0[6], c0e, 0, 0, 0);
        c1e = __builtin_amdgcn_mfma_f32_16x16x32_f16(A[6], wB1[6], c1e, 0, 0, 0);
        c0o = __builtin_amdgcn_mfma_f32_16x16x32_f16(A[7], wB0[7], c0o, 0, 0, 0);
        c1o = __builtin_amdgcn_mfma_f32_16x16x32_f16(A[7], wB1[7], c1o, 0, 0, 0);
        const f4v Y0 = c0e + c0o;   // y[steps 4g+reg][ch0]
        const f4v Y1 = c1e + c1o;   // y[steps 4g+reg][ch1]

        // R = dt*Y + du, cast to f16 (B operand of the L-MFMA, same layout)
        h4v rB0, rB1;
#pragma unroll
        for (int i = 0; i < 4; ++i) {
            rB0[i] = (_Float16)fmaf(dt, Y0[i], du0[i]);
            rB1[i] = (_Float16)fmaf(dt, Y1[i], du1[i]);
        }
        // C-in = a^{step+1} * xprev
        f4v ci0, ci1;
#pragma unroll
        for (int i = 0; i < 4; ++i) {
            ci0[i] = aC[i] * xq0;
            ci1[i] = aC[i] * xq1;
        }
        const f4v X0 = __builtin_amdgcn_mfma_f32_16x16x16f16(Lf, rB0, ci0, 0, 0, 0);
        const f4v X1 = __builtin_amdgcn_mfma_f32_16x16x16f16(Lf, rB1, ci1, 0, 0, 0);
        Xc0 = X0;
        Xc1 = X1;

        // tanh -> tx rows 4g+i+1 (row 16 skipped; row 0 refreshed at commit)
#pragma unroll
        for (int i = 0; i < 4; ++i) {
            const _Float16 t0 = tanh16(X0[i]);
            const _Float16 t1 = tanh16(X1[i]);
            if (i < 3 || g < 3) {
                *(_Float16*)((char*)txw + toff0[i]) = t0;
                *(_Float16*)((char*)txw + toff1[i]) = t1;
            }
        }
        asm volatile("s_waitcnt lgkmcnt(0)" ::: "memory");
        __builtin_amdgcn_s_barrier();
        __builtin_amdgcn_sched_barrier(0);
    };

    // ---- commit: X -> global (C-layout), row0 + xprev broadcast ----
    auto commit = [&](int s0) {
        const size_t base = ((size_t)(s0 >> 10) << 8);
        float* p0 = Xout + (base + ch0) * 1024 + (s0 & 1023) + 4 * g;
        float* p1 = Xout + (base + ch1) * 1024 + (s0 & 1023) + 4 * g;
        *(float4*)p0 = make_float4(Xc0[0], Xc0[1], Xc0[2], Xc0[3]);
        *(float4*)p1 = make_float4(Xc1[0], Xc1[1], Xc1[2], Xc1[3]);
        if (g == 3) {   // lanes holding step 15
            const _Float16 t0 = tanh16(Xc0[3]);
            const _Float16 t1 = tanh16(Xc1[3]);
            tx0[ch0] = t0; tx1[ch0] = t0;   // row-0 swizzle is identity
            tx0[ch1] = t1; tx1[ch1] = t1;
            xpb[ch0] = Xc0[3];
            xpb[ch1] = Xc1[3];
        }
        asm volatile("s_waitcnt lgkmcnt(0)" ::: "memory");  // intra-wave W->R
        xq0 = xpb[ch0];
        xq1 = xpb[ch1];
        asm volatile("s_waitcnt lgkmcnt(0)" ::: "memory");
        __builtin_amdgcn_s_barrier();
        __builtin_amdgcn_sched_barrier(0);
    };

    // Two blocks per loop; 3 iters flip predictor parity each block.
#pragma unroll 1
    for (int it = 0; it < NSTEP / (2 * BLK); ++it) {
        const int s0 = it * 2 * BLK;

        loadu(s0 + BLK, un0, un1);     // prefetch odd-block u
        iter(tx0, tx1);
        iter(tx1, tx0);
        iter(tx0, tx1);
        commit(s0);
        du0[0] = dt * un0.x; du0[1] = dt * un0.y; du0[2] = dt * un0.z; du0[3] = dt * un0.w;
        du1[0] = dt * un1.x; du1[1] = dt * un1.y; du1[2] = dt * un1.z; du1[3] = dt * un1.w;

        loadu(s0 + 2 * BLK, un0, un1); // prefetch next even (last overrun: out1, unused)
        iter(tx1, tx0);
        iter(tx0, tx1);
        iter(tx1, tx0);
        commit(s0 + BLK);
        du0[0] = dt * un0.x; du0[1] = dt * un0.y; du0[2] = dt * un0.z; du0[3] = dt * un0.w;
        du1[0] = dt * un1.x; du1[1] = dt * un1.y; du1[2] = dt * un1.z; du1[3] = dt * un1.w;
    }
}

// ---------------------------------------------------------------------------
extern "C" void kernel_launch(void* const* d_in, const int* in_sizes, int n_in,
                              void* d_out, int out_size, void* d_ws, size_t ws_size,
                              hipStream_t stream) {
    const float* u  = (const float*)d_in[0];
    const float* dt = (const float*)d_in[1];
    const float* W  = (const float*)d_in[2];
    const float* M  = (const float*)d_in[3];
    const float* H  = (const float*)d_in[4];
    const float* b  = (const float*)d_in[5];

    float* out0 = (float*)d_out;                        // outputs region (Y)
    float* out1 = out0 + (size_t)IQ * C_CH * T_SEQ;     // membrane region (X)

    dim3 ggrid(T_SEQ / 64, C_CH / 64, IQ);

    // 1) Uproj[iq][c][t] = M @ u_iq  -> staged in out0 (overwritten by Y later)
    gemm_ct<false><<<ggrid, 256, 0, stream>>>(M, u, nullptr, out0);

    // 2) Block-Picard scan over 65536 steps; membrane potentials -> out1
    scan_picard<<<1, 512, 0, stream>>>(W, out0, dt, out1);

    // 3) Y[iq][c][t] = sigmoid(H @ X_iq + b) -> out0
    gemm_ct<true><<<ggrid, 256, 0, stream>>>(H, out1, b, out0);
}